// Round 1
// baseline (7120.142 us; speedup 1.0000x reference)
//
#include <hip/hip_runtime.h>
#include <math.h>

#define N_SP 2304   // 48*48 spatial
#define HW 48

// ---------------------------------------------------------------------------
// Generic 1x1-conv GEMM: Y[b,o,n] = act( (sum_k W[o,k]*X[b,k,n]) * S[o] + B[o] ) (+ Res)
// X comes from X1 for k < K1, from X2 for k >= K1 (two-source for concat).
// ---------------------------------------------------------------------------
__global__ __launch_bounds__(256) void conv1x1_gemm(
    const float* __restrict__ X1, long x1_bstride,
    const float* __restrict__ X2, long x2_bstride, int K1,
    int K, int M,
    const float* __restrict__ W,
    const float* __restrict__ S,
    const float* __restrict__ Bi,
    const float* __restrict__ Res, long res_bstride,
    float* __restrict__ Y,
    int act)
{
    const int N = N_SP;
    __shared__ float Ws[16][65];
    __shared__ float Xs[16][65];
    int b  = blockIdx.z;
    int n0 = blockIdx.x * 64;
    int m0 = blockIdx.y * 64;
    int t  = threadIdx.x;
    int tx = t & 15, ty = t >> 4;

    float acc[4][4];
    #pragma unroll
    for (int r = 0; r < 4; ++r)
        #pragma unroll
        for (int c = 0; c < 4; ++c) acc[r][c] = 0.f;

    const float* x1b = X1 + (long)b * x1_bstride;
    const float* x2b = X2 ? (X2 + (long)b * x2_bstride) : nullptr;

    for (int k0 = 0; k0 < K; k0 += 16) {
        // W tile: Ws[kk][mm] = W[(m0+mm)*K + k0+kk]
        #pragma unroll
        for (int it = 0; it < 4; ++it) {
            int l  = t + 256 * it;
            int kk = l & 15, mm = l >> 4;
            Ws[kk][mm] = W[(long)(m0 + mm) * K + k0 + kk];
        }
        // X tile: Xs[kk][nn] = X[b, k0+kk, n0+nn]
        #pragma unroll
        for (int it = 0; it < 4; ++it) {
            int l  = t + 256 * it;
            int nn = l & 63, kk = l >> 6;
            int kg = k0 + kk;
            const float* src = (kg < K1) ? (x1b + (long)kg * N)
                                         : (x2b + (long)(kg - K1) * N);
            Xs[kk][nn] = src[n0 + nn];
        }
        __syncthreads();
        #pragma unroll
        for (int kk = 0; kk < 16; ++kk) {
            float a[4], bv[4];
            #pragma unroll
            for (int r = 0; r < 4; ++r) a[r]  = Ws[kk][ty + 16 * r];
            #pragma unroll
            for (int c = 0; c < 4; ++c) bv[c] = Xs[kk][tx + 16 * c];
            #pragma unroll
            for (int r = 0; r < 4; ++r)
                #pragma unroll
                for (int c = 0; c < 4; ++c) acc[r][c] += a[r] * bv[c];
        }
        __syncthreads();
    }

    long ybase = (long)b * M * N;
    #pragma unroll
    for (int r = 0; r < 4; ++r) {
        int o = m0 + ty + 16 * r;
        float sc = S[o], bi = Bi[o];
        #pragma unroll
        for (int c = 0; c < 4; ++c) {
            int n = n0 + tx + 16 * c;
            float y = acc[r][c] * sc + bi;
            if (act) y = y / (1.f + expf(-y));   // silu
            if (Res) y += Res[(long)b * res_bstride + (long)o * N + n];
            Y[ybase + (long)o * N + n] = y;
        }
    }
}

// ---------------------------------------------------------------------------
// Attention: one block per (query row i, (b,h)). key_dim=32, head_dim=64, N=2304.
// Scores live in 9 registers/thread (2304 = 9*256). Softmax over j, then PV.
// ---------------------------------------------------------------------------
__global__ __launch_bounds__(256) void attn_kernel(const float* __restrict__ qkv,
                                                   float* __restrict__ outp)
{
    const int N = N_SP;
    __shared__ float qs[32];
    __shared__ float red[4][64];
    __shared__ float wtmp[4];

    int i  = blockIdx.x;
    int bh = blockIdx.y;
    int b = bh >> 2, h = bh & 3;
    int t = threadIdx.x;
    int lane = t & 63, wid = t >> 6;
    const float scale = 0.17677669529663687f;  // 32^-0.5

    const float* base = qkv + (long)b * 512 * N;
    const float* krow = base + (long)(h * 128 + 32) * N;
    const float* vrow = base + (long)(h * 128 + 64) * N;

    if (t < 32) qs[t] = base[(long)(h * 128 + t) * N + i];
    __syncthreads();

    // scores for this thread's 9 columns
    float pj[9];
    float lm = -1e30f;
    #pragma unroll
    for (int jj = 0; jj < 9; ++jj) {
        int j = t + 256 * jj;
        float s = 0.f;
        #pragma unroll
        for (int d = 0; d < 32; ++d) s += qs[d] * krow[(long)d * N + j];
        s *= scale;
        pj[jj] = s;
        lm = fmaxf(lm, s);
    }
    // block max
    #pragma unroll
    for (int off = 32; off > 0; off >>= 1) lm = fmaxf(lm, __shfl_down(lm, off, 64));
    if (lane == 0) wtmp[wid] = lm;
    __syncthreads();
    float mx = fmaxf(fmaxf(wtmp[0], wtmp[1]), fmaxf(wtmp[2], wtmp[3]));
    __syncthreads();   // all threads have read wtmp before reuse

    float ls = 0.f;
    #pragma unroll
    for (int jj = 0; jj < 9; ++jj) {
        float p = expf(pj[jj] - mx);
        pj[jj] = p;
        ls += p;
    }
    #pragma unroll
    for (int off = 32; off > 0; off >>= 1) ls += __shfl_down(ls, off, 64);
    if (lane == 0) wtmp[wid] = ls;
    __syncthreads();
    float inv = 1.f / (wtmp[0] + wtmp[1] + wtmp[2] + wtmp[3]);

    // PV: acc[d] = sum_j p_j * v[d,j]
    float acc[64];
    #pragma unroll
    for (int d = 0; d < 64; ++d) acc[d] = 0.f;
    #pragma unroll
    for (int jj = 0; jj < 9; ++jj) {
        int j = t + 256 * jj;
        float p = pj[jj];
        #pragma unroll
        for (int d = 0; d < 64; ++d) acc[d] += p * vrow[(long)d * N + j];
    }
    #pragma unroll
    for (int d = 0; d < 64; ++d) {
        float v = acc[d];
        #pragma unroll
        for (int off = 32; off > 0; off >>= 1) v += __shfl_down(v, off, 64);
        if (lane == 0) red[wid][d] = v;
    }
    __syncthreads();
    if (t < 64) {
        float o = (red[0][t] + red[1][t] + red[2][t] + red[3][t]) * inv;
        outp[(long)b * 256 * N + (long)(h * 64 + t) * N + i] = o;
    }
}

// ---------------------------------------------------------------------------
// Depthwise 3x3 on v (read straight out of qkv with channel remap), *s+b,
// accumulated (+=) into the attention output buffer.
// ---------------------------------------------------------------------------
__global__ __launch_bounds__(256) void dwpe_kernel(const float* __restrict__ qkv,
    const float* __restrict__ pw, const float* __restrict__ ps,
    const float* __restrict__ pb, float* __restrict__ attnbuf)
{
    const int N = N_SP;
    int bc = blockIdx.x;
    int b = bc >> 8, c = bc & 255;
    int ch = ((c >> 6) * 128) + 64 + (c & 63);   // v channel inside qkv
    const float* src = qkv + (long)b * 512 * N + (long)ch * N;
    float w[9];
    #pragma unroll
    for (int k = 0; k < 9; ++k) w[k] = pw[c * 9 + k];
    float sc = ps[c], bi = pb[c];
    float* dst = attnbuf + (long)b * 256 * N + (long)c * N;

    for (int p = threadIdx.x; p < N; p += 256) {
        int y = p / HW, x = p - y * HW;
        float s = 0.f;
        #pragma unroll
        for (int dy = -1; dy <= 1; ++dy) {
            int yy = y + dy;
            if (yy < 0 || yy >= HW) continue;
            #pragma unroll
            for (int dx = -1; dx <= 1; ++dx) {
                int xx = x + dx;
                if (xx < 0 || xx >= HW) continue;
                s += w[(dy + 1) * 3 + (dx + 1)] * src[yy * HW + xx];
            }
        }
        dst[p] += s * sc + bi;
    }
}

// ---------------------------------------------------------------------------
extern "C" void kernel_launch(void* const* d_in, const int* in_sizes, int n_in,
                              void* d_out, int out_size, void* d_ws, size_t ws_size,
                              hipStream_t stream)
{
    const long N = N_SP;
    const float* x      = (const float*)d_in[0];
    const float* cv1_w  = (const float*)d_in[1];
    const float* cv1_s  = (const float*)d_in[2];
    const float* cv1_b  = (const float*)d_in[3];
    const float* qkv_w  = (const float*)d_in[4];
    const float* qkv_s  = (const float*)d_in[5];
    const float* qkv_b  = (const float*)d_in[6];
    const float* pe_w   = (const float*)d_in[7];
    const float* pe_s   = (const float*)d_in[8];
    const float* pe_b   = (const float*)d_in[9];
    const float* proj_w = (const float*)d_in[10];
    const float* proj_s = (const float*)d_in[11];
    const float* proj_b = (const float*)d_in[12];
    const float* ffn1_w = (const float*)d_in[13];
    const float* ffn1_s = (const float*)d_in[14];
    const float* ffn1_b = (const float*)d_in[15];
    const float* ffn2_w = (const float*)d_in[16];
    const float* ffn2_s = (const float*)d_in[17];
    const float* ffn2_b = (const float*)d_in[18];
    const float* cv2_w  = (const float*)d_in[19];
    const float* cv2_s  = (const float*)d_in[20];
    const float* cv2_b  = (const float*)d_in[21];
    float* out = (float*)d_out;
    float* ws  = (float*)d_ws;

    // workspace layout (floats)
    float* ab      = ws;                      // (4,512,N)
    float* qkvb    = ab      + 4L * 512 * N;  // (4,512,N)
    float* attnbuf = qkvb    + 4L * 512 * N;  // (4,256,N)
    float* bb2     = attnbuf + 4L * 256 * N;  // (4,256,N)
    float* fbuf    = bb2     + 4L * 256 * N;  // (4,512,N)
    float* bb3     = fbuf    + 4L * 512 * N;  // (4,256,N)

    dim3 blk(256);
    const int BIGK = 1 << 30;

    // 1. ab = silu(cv1(x))
    conv1x1_gemm<<<dim3(36, 8, 4), blk, 0, stream>>>(
        x, 512 * N, nullptr, 0, BIGK, 512, 512,
        cv1_w, cv1_s, cv1_b, nullptr, 0, ab, 1);

    // 2. qkv = conv(bb)   (bb = ab channels 256..511)
    conv1x1_gemm<<<dim3(36, 8, 4), blk, 0, stream>>>(
        ab + 256 * N, 512 * N, nullptr, 0, BIGK, 256, 512,
        qkv_w, qkv_s, qkv_b, nullptr, 0, qkvb, 0);

    // 3. attention core -> attnbuf
    attn_kernel<<<dim3(N_SP, 16), blk, 0, stream>>>(qkvb, attnbuf);

    // 4. attnbuf += dwconv3x3(v)*s+b
    dwpe_kernel<<<dim3(1024), blk, 0, stream>>>(qkvb, pe_w, pe_s, pe_b, attnbuf);

    // 5. bb2 = bb + proj(attnbuf)
    conv1x1_gemm<<<dim3(36, 4, 4), blk, 0, stream>>>(
        attnbuf, 256 * N, nullptr, 0, BIGK, 256, 256,
        proj_w, proj_s, proj_b, ab + 256 * N, 512 * N, bb2, 0);

    // 6. f = silu(ffn1(bb2))
    conv1x1_gemm<<<dim3(36, 8, 4), blk, 0, stream>>>(
        bb2, 256 * N, nullptr, 0, BIGK, 256, 512,
        ffn1_w, ffn1_s, ffn1_b, nullptr, 0, fbuf, 1);

    // 7. bb3 = bb2 + ffn2(f)
    conv1x1_gemm<<<dim3(36, 4, 4), blk, 0, stream>>>(
        fbuf, 512 * N, nullptr, 0, BIGK, 512, 256,
        ffn2_w, ffn2_s, ffn2_b, bb2, 256 * N, bb3, 0);

    // 8. out = silu(cv2(concat(a, bb3)))   (a = ab channels 0..255)
    conv1x1_gemm<<<dim3(36, 8, 4), blk, 0, stream>>>(
        ab, 512 * N, bb3, 256 * N, 256, 512, 512,
        cv2_w, cv2_s, cv2_b, nullptr, 0, out, 1);
}

// Round 2
// 1189.995 us; speedup vs baseline: 5.9833x; 5.9833x over previous
//
#include <hip/hip_runtime.h>
#include <math.h>

#define N_SP 2304   // 48*48 spatial
#define HW 48

// ---------------------------------------------------------------------------
// Generic 1x1-conv GEMM: Y[b,o,n] = act( (sum_k W[o,k]*X[b,k,n]) * S[o] + B[o] ) (+ Res)
// X comes from X1 for k < K1, from X2 for k >= K1 (two-source for concat).
// ---------------------------------------------------------------------------
__global__ __launch_bounds__(256) void conv1x1_gemm(
    const float* __restrict__ X1, long x1_bstride,
    const float* __restrict__ X2, long x2_bstride, int K1,
    int K, int M,
    const float* __restrict__ W,
    const float* __restrict__ S,
    const float* __restrict__ Bi,
    const float* __restrict__ Res, long res_bstride,
    float* __restrict__ Y,
    int act)
{
    const int N = N_SP;
    __shared__ float Ws[16][65];
    __shared__ float Xs[16][65];
    int b  = blockIdx.z;
    int n0 = blockIdx.x * 64;
    int m0 = blockIdx.y * 64;
    int t  = threadIdx.x;
    int tx = t & 15, ty = t >> 4;

    float acc[4][4];
    #pragma unroll
    for (int r = 0; r < 4; ++r)
        #pragma unroll
        for (int c = 0; c < 4; ++c) acc[r][c] = 0.f;

    const float* x1b = X1 + (long)b * x1_bstride;
    const float* x2b = X2 ? (X2 + (long)b * x2_bstride) : nullptr;

    for (int k0 = 0; k0 < K; k0 += 16) {
        // W tile: Ws[kk][mm] = W[(m0+mm)*K + k0+kk]
        #pragma unroll
        for (int it = 0; it < 4; ++it) {
            int l  = t + 256 * it;
            int kk = l & 15, mm = l >> 4;
            Ws[kk][mm] = W[(long)(m0 + mm) * K + k0 + kk];
        }
        // X tile: Xs[kk][nn] = X[b, k0+kk, n0+nn]
        #pragma unroll
        for (int it = 0; it < 4; ++it) {
            int l  = t + 256 * it;
            int nn = l & 63, kk = l >> 6;
            int kg = k0 + kk;
            const float* src = (kg < K1) ? (x1b + (long)kg * N)
                                         : (x2b + (long)(kg - K1) * N);
            Xs[kk][nn] = src[n0 + nn];
        }
        __syncthreads();
        #pragma unroll
        for (int kk = 0; kk < 16; ++kk) {
            float a[4], bv[4];
            #pragma unroll
            for (int r = 0; r < 4; ++r) a[r]  = Ws[kk][ty + 16 * r];
            #pragma unroll
            for (int c = 0; c < 4; ++c) bv[c] = Xs[kk][tx + 16 * c];
            #pragma unroll
            for (int r = 0; r < 4; ++r)
                #pragma unroll
                for (int c = 0; c < 4; ++c) acc[r][c] += a[r] * bv[c];
        }
        __syncthreads();
    }

    long ybase = (long)b * M * N;
    #pragma unroll
    for (int r = 0; r < 4; ++r) {
        int o = m0 + ty + 16 * r;
        float sc = S[o], bi = Bi[o];
        #pragma unroll
        for (int c = 0; c < 4; ++c) {
            int n = n0 + tx + 16 * c;
            float y = acc[r][c] * sc + bi;
            if (act) y = y / (1.f + expf(-y));   // silu
            if (Res) y += Res[(long)b * res_bstride + (long)o * N + n];
            Y[ybase + (long)o * N + n] = y;
        }
    }
}

// ---------------------------------------------------------------------------
// Flash attention: one block per ((b,h), 64-query tile). key_dim=32, head_dim=64.
// 16x16 thread grid, 4x4 microtiles for QK^T and PV, online softmax with
// 16-lane shfl_xor row reductions. K/V staged in LDS in 64-col tiles.
// ---------------------------------------------------------------------------
__global__ __launch_bounds__(256) void attn_flash(const float* __restrict__ qkv,
                                                  float* __restrict__ outp)
{
    const int N = N_SP;
    __shared__ float Qs[32][68];   // Qs[d][r], pre-scaled
    __shared__ float Ks[32][68];   // Ks[d][jj]
    __shared__ float Vs[64][68];   // Vs[d][jj]
    __shared__ float Ps[64][68];   // Ps[jj][r]
    __shared__ float srow[64];
    __shared__ float lrow[64];

    const int i0 = blockIdx.x * 64;
    const int bh = blockIdx.y;
    const int b = bh >> 2, h = bh & 3;
    const int t = threadIdx.x;
    const int tx = t & 15, ty = t >> 4;
    const float scale = 0.17677669529663687f;   // 32^-0.5

    const float* qp = qkv + ((long)b * 512 + (long)h * 128) * N;
    const float* kp = qp + 32L * N;
    const float* vp = qp + 64L * N;

    // Q tile: Qs[d][r] = q[d][i0+r] * scale   (512 float4 loads)
    #pragma unroll
    for (int it = 0; it < 2; ++it) {
        int idx = t + 256 * it;                 // 0..511
        int d = idx >> 4, j4 = (idx & 15) << 2;
        float4 v = *reinterpret_cast<const float4*>(qp + (long)d * N + i0 + j4);
        v.x *= scale; v.y *= scale; v.z *= scale; v.w *= scale;
        *reinterpret_cast<float4*>(&Qs[d][j4]) = v;
    }

    float m_[4], l_[4], acc[4][4];
    #pragma unroll
    for (int u = 0; u < 4; ++u) { m_[u] = -1e30f; l_[u] = 0.f; }
    #pragma unroll
    for (int u = 0; u < 4; ++u)
        #pragma unroll
        for (int c = 0; c < 4; ++c) acc[u][c] = 0.f;

    for (int j0 = 0; j0 < N; j0 += 64) {
        // ---- stage K (2048 floats) and V (4096 floats) as float4 ----
        #pragma unroll
        for (int it = 0; it < 2; ++it) {
            int idx = t + 256 * it;
            int d = idx >> 4, j4 = (idx & 15) << 2;
            float4 v = *reinterpret_cast<const float4*>(kp + (long)d * N + j0 + j4);
            *reinterpret_cast<float4*>(&Ks[d][j4]) = v;
        }
        #pragma unroll
        for (int it = 0; it < 4; ++it) {
            int idx = t + 256 * it;                 // 0..1023
            int d = idx >> 4, j4 = (idx & 15) << 2;
            float4 v = *reinterpret_cast<const float4*>(vp + (long)d * N + j0 + j4);
            *reinterpret_cast<float4*>(&Vs[d][j4]) = v;
        }
        __syncthreads();

        // ---- QK^T: s[u][c] = score[row ty+16u][col tx+16c] ----
        float s[4][4];
        #pragma unroll
        for (int u = 0; u < 4; ++u)
            #pragma unroll
            for (int c = 0; c < 4; ++c) s[u][c] = 0.f;
        #pragma unroll
        for (int d = 0; d < 32; ++d) {
            float a[4], bv[4];
            #pragma unroll
            for (int u = 0; u < 4; ++u) a[u]  = Qs[d][ty + 16 * u];
            #pragma unroll
            for (int c = 0; c < 4; ++c) bv[c] = Ks[d][tx + 16 * c];
            #pragma unroll
            for (int u = 0; u < 4; ++u)
                #pragma unroll
                for (int c = 0; c < 4; ++c) s[u][c] += a[u] * bv[c];
        }

        const int last = (j0 + 64 >= N);
        // ---- online softmax stats per row (16 lanes share a row group) ----
        #pragma unroll
        for (int u = 0; u < 4; ++u) {
            float tm = fmaxf(fmaxf(s[u][0], s[u][1]), fmaxf(s[u][2], s[u][3]));
            #pragma unroll
            for (int mask = 1; mask < 16; mask <<= 1)
                tm = fmaxf(tm, __shfl_xor(tm, mask, 16));
            float mnew = fmaxf(m_[u], tm);
            float scl  = __expf(m_[u] - mnew);
            float p0 = __expf(s[u][0] - mnew);
            float p1 = __expf(s[u][1] - mnew);
            float p2 = __expf(s[u][2] - mnew);
            float p3 = __expf(s[u][3] - mnew);
            float ts = (p0 + p1) + (p2 + p3);
            #pragma unroll
            for (int mask = 1; mask < 16; mask <<= 1)
                ts += __shfl_xor(ts, mask, 16);
            l_[u] = l_[u] * scl + ts;
            m_[u] = mnew;
            Ps[tx +  0][ty + 16 * u] = p0;
            Ps[tx + 16][ty + 16 * u] = p1;
            Ps[tx + 32][ty + 16 * u] = p2;
            Ps[tx + 48][ty + 16 * u] = p3;
            if (tx == 0) {
                srow[ty + 16 * u] = scl;
                if (last) lrow[ty + 16 * u] = l_[u];
            }
        }
        __syncthreads();

        // ---- PV: acc[u][c] over dims d=ty+16u, rows r=tx+16c ----
        #pragma unroll
        for (int c = 0; c < 4; ++c) {
            float f = srow[tx + 16 * c];
            #pragma unroll
            for (int u = 0; u < 4; ++u) acc[u][c] *= f;
        }
        #pragma unroll
        for (int jj = 0; jj < 64; ++jj) {
            float a[4], pv[4];
            #pragma unroll
            for (int u = 0; u < 4; ++u) a[u]  = Vs[ty + 16 * u][jj];
            #pragma unroll
            for (int c = 0; c < 4; ++c) pv[c] = Ps[jj][tx + 16 * c];
            #pragma unroll
            for (int u = 0; u < 4; ++u)
                #pragma unroll
                for (int c = 0; c < 4; ++c) acc[u][c] += a[u] * pv[c];
        }
        __syncthreads();
    }

    // ---- epilogue: divide by row sums, write out[d][i0+r] ----
    #pragma unroll
    for (int c = 0; c < 4; ++c) {
        float inv = 1.f / lrow[tx + 16 * c];
        #pragma unroll
        for (int u = 0; u < 4; ++u) {
            int d = ty + 16 * u, r = tx + 16 * c;
            outp[((long)b * 256 + (long)h * 64 + d) * N + i0 + r] = acc[u][c] * inv;
        }
    }
}

// ---------------------------------------------------------------------------
// Depthwise 3x3 on v (read straight out of qkv with channel remap), *s+b,
// accumulated (+=) into the attention output buffer.
// ---------------------------------------------------------------------------
__global__ __launch_bounds__(256) void dwpe_kernel(const float* __restrict__ qkv,
    const float* __restrict__ pw, const float* __restrict__ ps,
    const float* __restrict__ pb, float* __restrict__ attnbuf)
{
    const int N = N_SP;
    int bc = blockIdx.x;
    int b = bc >> 8, c = bc & 255;
    int ch = ((c >> 6) * 128) + 64 + (c & 63);   // v channel inside qkv
    const float* src = qkv + (long)b * 512 * N + (long)ch * N;
    float w[9];
    #pragma unroll
    for (int k = 0; k < 9; ++k) w[k] = pw[c * 9 + k];
    float sc = ps[c], bi = pb[c];
    float* dst = attnbuf + (long)b * 256 * N + (long)c * N;

    for (int p = threadIdx.x; p < N; p += 256) {
        int y = p / HW, x = p - y * HW;
        float s = 0.f;
        #pragma unroll
        for (int dy = -1; dy <= 1; ++dy) {
            int yy = y + dy;
            if (yy < 0 || yy >= HW) continue;
            #pragma unroll
            for (int dx = -1; dx <= 1; ++dx) {
                int xx = x + dx;
                if (xx < 0 || xx >= HW) continue;
                s += w[(dy + 1) * 3 + (dx + 1)] * src[yy * HW + xx];
            }
        }
        dst[p] += s * sc + bi;
    }
}

// ---------------------------------------------------------------------------
extern "C" void kernel_launch(void* const* d_in, const int* in_sizes, int n_in,
                              void* d_out, int out_size, void* d_ws, size_t ws_size,
                              hipStream_t stream)
{
    const long N = N_SP;
    const float* x      = (const float*)d_in[0];
    const float* cv1_w  = (const float*)d_in[1];
    const float* cv1_s  = (const float*)d_in[2];
    const float* cv1_b  = (const float*)d_in[3];
    const float* qkv_w  = (const float*)d_in[4];
    const float* qkv_s  = (const float*)d_in[5];
    const float* qkv_b  = (const float*)d_in[6];
    const float* pe_w   = (const float*)d_in[7];
    const float* pe_s   = (const float*)d_in[8];
    const float* pe_b   = (const float*)d_in[9];
    const float* proj_w = (const float*)d_in[10];
    const float* proj_s = (const float*)d_in[11];
    const float* proj_b = (const float*)d_in[12];
    const float* ffn1_w = (const float*)d_in[13];
    const float* ffn1_s = (const float*)d_in[14];
    const float* ffn1_b = (const float*)d_in[15];
    const float* ffn2_w = (const float*)d_in[16];
    const float* ffn2_s = (const float*)d_in[17];
    const float* ffn2_b = (const float*)d_in[18];
    const float* cv2_w  = (const float*)d_in[19];
    const float* cv2_s  = (const float*)d_in[20];
    const float* cv2_b  = (const float*)d_in[21];
    float* out = (float*)d_out;
    float* ws  = (float*)d_ws;

    // workspace layout (floats)
    float* ab      = ws;                      // (4,512,N)
    float* qkvb    = ab      + 4L * 512 * N;  // (4,512,N)
    float* attnbuf = qkvb    + 4L * 512 * N;  // (4,256,N)
    float* bb2     = attnbuf + 4L * 256 * N;  // (4,256,N)
    float* fbuf    = bb2     + 4L * 256 * N;  // (4,512,N)
    float* bb3     = fbuf    + 4L * 512 * N;  // (4,256,N)

    dim3 blk(256);
    const int BIGK = 1 << 30;

    // 1. ab = silu(cv1(x))
    conv1x1_gemm<<<dim3(36, 8, 4), blk, 0, stream>>>(
        x, 512 * N, nullptr, 0, BIGK, 512, 512,
        cv1_w, cv1_s, cv1_b, nullptr, 0, ab, 1);

    // 2. qkv = conv(bb)   (bb = ab channels 256..511)
    conv1x1_gemm<<<dim3(36, 8, 4), blk, 0, stream>>>(
        ab + 256 * N, 512 * N, nullptr, 0, BIGK, 256, 512,
        qkv_w, qkv_s, qkv_b, nullptr, 0, qkvb, 0);

    // 3. attention core -> attnbuf
    attn_flash<<<dim3(36, 16), blk, 0, stream>>>(qkvb, attnbuf);

    // 4. attnbuf += dwconv3x3(v)*s+b
    dwpe_kernel<<<dim3(1024), blk, 0, stream>>>(qkvb, pe_w, pe_s, pe_b, attnbuf);

    // 5. bb2 = bb + proj(attnbuf)
    conv1x1_gemm<<<dim3(36, 4, 4), blk, 0, stream>>>(
        attnbuf, 256 * N, nullptr, 0, BIGK, 256, 256,
        proj_w, proj_s, proj_b, ab + 256 * N, 512 * N, bb2, 0);

    // 6. f = silu(ffn1(bb2))
    conv1x1_gemm<<<dim3(36, 8, 4), blk, 0, stream>>>(
        bb2, 256 * N, nullptr, 0, BIGK, 256, 512,
        ffn1_w, ffn1_s, ffn1_b, nullptr, 0, fbuf, 1);

    // 7. bb3 = bb2 + ffn2(f)
    conv1x1_gemm<<<dim3(36, 4, 4), blk, 0, stream>>>(
        fbuf, 512 * N, nullptr, 0, BIGK, 512, 256,
        ffn2_w, ffn2_s, ffn2_b, bb2, 256 * N, bb3, 0);

    // 8. out = silu(cv2(concat(a, bb3)))   (a = ab channels 0..255)
    conv1x1_gemm<<<dim3(36, 8, 4), blk, 0, stream>>>(
        ab, 512 * N, bb3, 256 * N, 256, 512, 512,
        cv2_w, cv2_s, cv2_b, nullptr, 0, out, 1);
}

// Round 3
// 517.501 us; speedup vs baseline: 13.7587x; 2.2995x over previous
//
#include <hip/hip_runtime.h>
#include <math.h>

#define N_SP 2304   // 48*48 spatial
#define HW 48

typedef short bf16x8 __attribute__((ext_vector_type(8)));
typedef short s4v    __attribute__((ext_vector_type(4)));
typedef float f32x4  __attribute__((ext_vector_type(4)));

// fp32 -> bf16 bits, round-to-nearest-even
__device__ __forceinline__ short f2bf(float x) {
    unsigned u = __float_as_uint(x);
    u += 0x7FFFu + ((u >> 16) & 1u);
    return (short)(u >> 16);
}

// ---------------------------------------------------------------------------
// Generic 1x1-conv GEMM: Y[b,o,n] = act( (sum_k W[o,k]*X[b,k,n]) * S[o] + B[o] ) (+ Res)
// X comes from X1 for k < K1, from X2 for k >= K1 (two-source for concat).
// ---------------------------------------------------------------------------
__global__ __launch_bounds__(256) void conv1x1_gemm(
    const float* __restrict__ X1, long x1_bstride,
    const float* __restrict__ X2, long x2_bstride, int K1,
    int K, int M,
    const float* __restrict__ W,
    const float* __restrict__ S,
    const float* __restrict__ Bi,
    const float* __restrict__ Res, long res_bstride,
    float* __restrict__ Y,
    int act)
{
    const int N = N_SP;
    __shared__ float Ws[16][65];
    __shared__ float Xs[16][65];
    int b  = blockIdx.z;
    int n0 = blockIdx.x * 64;
    int m0 = blockIdx.y * 64;
    int t  = threadIdx.x;
    int tx = t & 15, ty = t >> 4;

    float acc[4][4];
    #pragma unroll
    for (int r = 0; r < 4; ++r)
        #pragma unroll
        for (int c = 0; c < 4; ++c) acc[r][c] = 0.f;

    const float* x1b = X1 + (long)b * x1_bstride;
    const float* x2b = X2 ? (X2 + (long)b * x2_bstride) : nullptr;

    for (int k0 = 0; k0 < K; k0 += 16) {
        #pragma unroll
        for (int it = 0; it < 4; ++it) {
            int l  = t + 256 * it;
            int kk = l & 15, mm = l >> 4;
            Ws[kk][mm] = W[(long)(m0 + mm) * K + k0 + kk];
        }
        #pragma unroll
        for (int it = 0; it < 4; ++it) {
            int l  = t + 256 * it;
            int nn = l & 63, kk = l >> 6;
            int kg = k0 + kk;
            const float* src = (kg < K1) ? (x1b + (long)kg * N)
                                         : (x2b + (long)(kg - K1) * N);
            Xs[kk][nn] = src[n0 + nn];
        }
        __syncthreads();
        #pragma unroll
        for (int kk = 0; kk < 16; ++kk) {
            float a[4], bv[4];
            #pragma unroll
            for (int r = 0; r < 4; ++r) a[r]  = Ws[kk][ty + 16 * r];
            #pragma unroll
            for (int c = 0; c < 4; ++c) bv[c] = Xs[kk][tx + 16 * c];
            #pragma unroll
            for (int r = 0; r < 4; ++r)
                #pragma unroll
                for (int c = 0; c < 4; ++c) acc[r][c] += a[r] * bv[c];
        }
        __syncthreads();
    }

    long ybase = (long)b * M * N;
    #pragma unroll
    for (int r = 0; r < 4; ++r) {
        int o = m0 + ty + 16 * r;
        float sc = S[o], bi = Bi[o];
        #pragma unroll
        for (int c = 0; c < 4; ++c) {
            int n = n0 + tx + 16 * c;
            float y = acc[r][c] * sc + bi;
            if (act) y = y / (1.f + expf(-y));   // silu
            if (Res) y += Res[(long)b * res_bstride + (long)o * N + n];
            Y[ybase + (long)o * N + n] = y;
        }
    }
}

// ---------------------------------------------------------------------------
// MFMA flash attention. Block = 256 thr (4 waves) handles one (b,h) x 64 queries.
// Swapped QK^T (S^T = mfma(K, Q)) so each lane owns softmax rows lane-locally.
// kd=32 = one 16x16x32 MFMA K-step. PV uses a chosen k-permutation matching
// P's C/D register layout (consistency between A and B frags is all MFMA needs).
// ---------------------------------------------------------------------------
__global__ __launch_bounds__(256) void attn_mfma(const float* __restrict__ qkv,
                                                 float* __restrict__ outp)
{
    const int N = N_SP;
    __shared__ unsigned short Klds[64][40];   // [j][d], pad 40 (80B rows, 16B-aligned)
    __shared__ unsigned short Vlds[64][68];   // [d][j], pad 68 (136B rows, 8B-aligned)

    const int i0 = blockIdx.x * 64;
    const int bh = blockIdx.y;
    const int b = bh >> 2, h = bh & 3;
    const int t = threadIdx.x;
    const int w = t >> 6;           // wave 0..3 -> query sub-tile
    const int lane = t & 63;
    const int li = lane & 15;       // MFMA m/n index
    const int g  = lane >> 4;       // MFMA k-group
    // scale * log2(e): softmax done in exp2 domain
    const float qscale = 0.17677669529663687f * 1.4426950408889634f;

    const float* qp = qkv + ((long)b * 512 + (long)h * 128) * N;
    const float* kp = qp + 32L * N;
    const float* vp = qp + 64L * N;

    const int i = i0 + w * 16 + li;

    // Q fragment (B operand): qf[r] = Q[8g+r][i] * qscale  (per-wave, loaded once)
    bf16x8 qf;
    #pragma unroll
    for (int r = 0; r < 8; ++r)
        qf[r] = f2bf(qp[(long)(8 * g + r) * N + i] * qscale);

    f32x4 oacc[4];
    #pragma unroll
    for (int dt = 0; dt < 4; ++dt) oacc[dt] = f32x4{0.f, 0.f, 0.f, 0.f};
    float m_run = -1e30f, l_run = 0.f;

    // staging register prefetch (tile 0)
    const int kd  = t >> 3;            // 0..31
    const int kjb = (t & 7) * 8;       // 0..56
    const int vd  = t >> 2;            // 0..63
    const int vjb = (t & 3) * 16;      // 0..48
    float4 kr0, kr1, vr[4];
    {
        const float* ks = kp + (long)kd * N + kjb;
        kr0 = *(const float4*)(ks);
        kr1 = *(const float4*)(ks + 4);
        const float* vs = vp + (long)vd * N + vjb;
        #pragma unroll
        for (int u = 0; u < 4; ++u) vr[u] = *(const float4*)(vs + 4 * u);
    }

    for (int j0 = 0; j0 < N; j0 += 64) {
        __syncthreads();   // previous tile's LDS readers done
        // ---- write staged regs -> LDS (bf16) ----
        Klds[kjb + 0][kd] = f2bf(kr0.x);
        Klds[kjb + 1][kd] = f2bf(kr0.y);
        Klds[kjb + 2][kd] = f2bf(kr0.z);
        Klds[kjb + 3][kd] = f2bf(kr0.w);
        Klds[kjb + 4][kd] = f2bf(kr1.x);
        Klds[kjb + 5][kd] = f2bf(kr1.y);
        Klds[kjb + 6][kd] = f2bf(kr1.z);
        Klds[kjb + 7][kd] = f2bf(kr1.w);
        #pragma unroll
        for (int u = 0; u < 4; ++u) {
            s4v pk;
            pk[0] = f2bf(vr[u].x); pk[1] = f2bf(vr[u].y);
            pk[2] = f2bf(vr[u].z); pk[3] = f2bf(vr[u].w);
            *(s4v*)&Vlds[vd][vjb + 4 * u] = pk;
        }
        // ---- prefetch next tile while computing this one ----
        if (j0 + 64 < N) {
            const float* ks = kp + (long)kd * N + (j0 + 64) + kjb;
            kr0 = *(const float4*)(ks);
            kr1 = *(const float4*)(ks + 4);
            const float* vs = vp + (long)vd * N + (j0 + 64) + vjb;
            #pragma unroll
            for (int u = 0; u < 4; ++u) vr[u] = *(const float4*)(vs + 4 * u);
        }
        __syncthreads();   // LDS tile ready

        // ---- QK^T swapped: sacc[js] = S^T[j-subtile][i]  (A=K^T, B=Q) ----
        f32x4 sacc[4];
        #pragma unroll
        for (int js = 0; js < 4; ++js) {
            bf16x8 kf = *(const bf16x8*)&Klds[js * 16 + li][8 * g];
            f32x4 z = f32x4{0.f, 0.f, 0.f, 0.f};
            sacc[js] = __builtin_amdgcn_mfma_f32_16x16x32_bf16(kf, qf, z, 0, 0, 0);
        }
        // lane holds S2[j = js*16 + 4g + r][i] (log2-domain scores)

        // ---- online softmax over j for this lane's i ----
        float tm = -1e30f;
        #pragma unroll
        for (int js = 0; js < 4; ++js)
            #pragma unroll
            for (int r = 0; r < 4; ++r) tm = fmaxf(tm, sacc[js][r]);
        tm = fmaxf(tm, __shfl_xor(tm, 16, 64));
        tm = fmaxf(tm, __shfl_xor(tm, 32, 64));
        float mnew = fmaxf(m_run, tm);
        float scl  = exp2f(m_run - mnew);
        float pl[4][4];
        float ts = 0.f;
        #pragma unroll
        for (int js = 0; js < 4; ++js)
            #pragma unroll
            for (int r = 0; r < 4; ++r) {
                float p = exp2f(sacc[js][r] - mnew);
                pl[js][r] = p;
                ts += p;
            }
        ts += __shfl_xor(ts, 16, 64);
        ts += __shfl_xor(ts, 32, 64);
        l_run = l_run * scl + ts;
        m_run = mnew;
        #pragma unroll
        for (int dt = 0; dt < 4; ++dt) oacc[dt] *= scl;

        // ---- PV: O^T += mfma(V, P^T); k-permutation chosen to match P layout ----
        #pragma unroll
        for (int ks = 0; ks < 2; ++ks) {
            bf16x8 pf;
            #pragma unroll
            for (int r = 0; r < 4; ++r) {
                pf[r]     = f2bf(pl[2 * ks][r]);      // j = (2ks)*16   + 4g + r
                pf[4 + r] = f2bf(pl[2 * ks + 1][r]);  // j = (2ks+1)*16 + 4g + r
            }
            #pragma unroll
            for (int dt = 0; dt < 4; ++dt) {
                int d = dt * 16 + li;
                s4v lo = *(const s4v*)&Vlds[d][32 * ks + 4 * g];       // same j's
                s4v hi = *(const s4v*)&Vlds[d][32 * ks + 16 + 4 * g];
                bf16x8 vf = __builtin_shufflevector(lo, hi, 0, 1, 2, 3, 4, 5, 6, 7);
                oacc[dt] = __builtin_amdgcn_mfma_f32_16x16x32_bf16(vf, pf, oacc[dt], 0, 0, 0);
            }
        }
    }

    // ---- epilogue: lane holds O[d = dt*16 + 4g + r][i] ----
    float inv = 1.f / l_run;
    long obase = ((long)b * 256 + (long)h * 64) * N + i;
    #pragma unroll
    for (int dt = 0; dt < 4; ++dt)
        #pragma unroll
        for (int r = 0; r < 4; ++r)
            outp[obase + (long)(dt * 16 + 4 * g + r) * N] = oacc[dt][r] * inv;
}

// ---------------------------------------------------------------------------
// Depthwise 3x3 on v (read straight out of qkv with channel remap), *s+b,
// accumulated (+=) into the attention output buffer.
// ---------------------------------------------------------------------------
__global__ __launch_bounds__(256) void dwpe_kernel(const float* __restrict__ qkv,
    const float* __restrict__ pw, const float* __restrict__ ps,
    const float* __restrict__ pb, float* __restrict__ attnbuf)
{
    const int N = N_SP;
    int bc = blockIdx.x;
    int b = bc >> 8, c = bc & 255;
    int ch = ((c >> 6) * 128) + 64 + (c & 63);   // v channel inside qkv
    const float* src = qkv + (long)b * 512 * N + (long)ch * N;
    float w[9];
    #pragma unroll
    for (int k = 0; k < 9; ++k) w[k] = pw[c * 9 + k];
    float sc = ps[c], bi = pb[c];
    float* dst = attnbuf + (long)b * 256 * N + (long)c * N;

    for (int p = threadIdx.x; p < N; p += 256) {
        int y = p / HW, x = p - y * HW;
        float s = 0.f;
        #pragma unroll
        for (int dy = -1; dy <= 1; ++dy) {
            int yy = y + dy;
            if (yy < 0 || yy >= HW) continue;
            #pragma unroll
            for (int dx = -1; dx <= 1; ++dx) {
                int xx = x + dx;
                if (xx < 0 || xx >= HW) continue;
                s += w[(dy + 1) * 3 + (dx + 1)] * src[yy * HW + xx];
            }
        }
        dst[p] += s * sc + bi;
    }
}

// ---------------------------------------------------------------------------
extern "C" void kernel_launch(void* const* d_in, const int* in_sizes, int n_in,
                              void* d_out, int out_size, void* d_ws, size_t ws_size,
                              hipStream_t stream)
{
    const long N = N_SP;
    const float* x      = (const float*)d_in[0];
    const float* cv1_w  = (const float*)d_in[1];
    const float* cv1_s  = (const float*)d_in[2];
    const float* cv1_b  = (const float*)d_in[3];
    const float* qkv_w  = (const float*)d_in[4];
    const float* qkv_s  = (const float*)d_in[5];
    const float* qkv_b  = (const float*)d_in[6];
    const float* pe_w   = (const float*)d_in[7];
    const float* pe_s   = (const float*)d_in[8];
    const float* pe_b   = (const float*)d_in[9];
    const float* proj_w = (const float*)d_in[10];
    const float* proj_s = (const float*)d_in[11];
    const float* proj_b = (const float*)d_in[12];
    const float* ffn1_w = (const float*)d_in[13];
    const float* ffn1_s = (const float*)d_in[14];
    const float* ffn1_b = (const float*)d_in[15];
    const float* ffn2_w = (const float*)d_in[16];
    const float* ffn2_s = (const float*)d_in[17];
    const float* ffn2_b = (const float*)d_in[18];
    const float* cv2_w  = (const float*)d_in[19];
    const float* cv2_s  = (const float*)d_in[20];
    const float* cv2_b  = (const float*)d_in[21];
    float* out = (float*)d_out;
    float* ws  = (float*)d_ws;

    // workspace layout (floats)
    float* ab      = ws;                      // (4,512,N)
    float* qkvb    = ab      + 4L * 512 * N;  // (4,512,N)
    float* attnbuf = qkvb    + 4L * 512 * N;  // (4,256,N)
    float* bb2     = attnbuf + 4L * 256 * N;  // (4,256,N)
    float* fbuf    = bb2     + 4L * 256 * N;  // (4,512,N)
    float* bb3     = fbuf    + 4L * 512 * N;  // (4,256,N)

    dim3 blk(256);
    const int BIGK = 1 << 30;

    // 1. ab = silu(cv1(x))
    conv1x1_gemm<<<dim3(36, 8, 4), blk, 0, stream>>>(
        x, 512 * N, nullptr, 0, BIGK, 512, 512,
        cv1_w, cv1_s, cv1_b, nullptr, 0, ab, 1);

    // 2. qkv = conv(bb)   (bb = ab channels 256..511)
    conv1x1_gemm<<<dim3(36, 8, 4), blk, 0, stream>>>(
        ab + 256 * N, 512 * N, nullptr, 0, BIGK, 256, 512,
        qkv_w, qkv_s, qkv_b, nullptr, 0, qkvb, 0);

    // 3. attention core -> attnbuf
    attn_mfma<<<dim3(36, 16), blk, 0, stream>>>(qkvb, attnbuf);

    // 4. attnbuf += dwconv3x3(v)*s+b
    dwpe_kernel<<<dim3(1024), blk, 0, stream>>>(qkvb, pe_w, pe_s, pe_b, attnbuf);

    // 5. bb2 = bb + proj(attnbuf)
    conv1x1_gemm<<<dim3(36, 4, 4), blk, 0, stream>>>(
        attnbuf, 256 * N, nullptr, 0, BIGK, 256, 256,
        proj_w, proj_s, proj_b, ab + 256 * N, 512 * N, bb2, 0);

    // 6. f = silu(ffn1(bb2))
    conv1x1_gemm<<<dim3(36, 8, 4), blk, 0, stream>>>(
        bb2, 256 * N, nullptr, 0, BIGK, 256, 512,
        ffn1_w, ffn1_s, ffn1_b, nullptr, 0, fbuf, 1);

    // 7. bb3 = bb2 + ffn2(f)
    conv1x1_gemm<<<dim3(36, 4, 4), blk, 0, stream>>>(
        fbuf, 512 * N, nullptr, 0, BIGK, 512, 256,
        ffn2_w, ffn2_s, ffn2_b, bb2, 256 * N, bb3, 0);

    // 8. out = silu(cv2(concat(a, bb3)))   (a = ab channels 0..255)
    conv1x1_gemm<<<dim3(36, 8, 4), blk, 0, stream>>>(
        ab, 512 * N, bb3, 256 * N, 256, 512, 512,
        cv2_w, cv2_s, cv2_b, nullptr, 0, out, 1);
}

// Round 4
// 207.514 us; speedup vs baseline: 34.3116x; 2.4938x over previous
//
#include <hip/hip_runtime.h>
#include <math.h>

#define N_SP 2304   // 48*48 spatial
#define HW 48

typedef unsigned short u16;
typedef short s8v  __attribute__((ext_vector_type(8)));   // bf16x8 (MFMA operand)
typedef short s4v  __attribute__((ext_vector_type(4)));   // bf16x4
typedef u16   u16x8 __attribute__((ext_vector_type(8)));
typedef float f32x4 __attribute__((ext_vector_type(4)));

__device__ __forceinline__ short f2bf(float x) {
    unsigned u = __float_as_uint(x);
    u += 0x7FFFu + ((u >> 16) & 1u);
    return (short)(u >> 16);
}
__device__ __forceinline__ float bf2f(u16 u) {
    return __uint_as_float((unsigned)u << 16);
}

// ---------------------------------------------------------------------------
// Weight fp32 -> bf16 (all six weight matrices in one launch, float4 chunks)
// ---------------------------------------------------------------------------
__global__ __launch_bounds__(256) void cvt_w(
    const float* __restrict__ s0, const float* __restrict__ s1,
    const float* __restrict__ s2, const float* __restrict__ s3,
    const float* __restrict__ s4, const float* __restrict__ s5,
    u16* __restrict__ d0, u16* __restrict__ d1, u16* __restrict__ d2,
    u16* __restrict__ d3, u16* __restrict__ d4, u16* __restrict__ d5)
{
    int id = blockIdx.x * 256 + threadIdx.x;   // float4 index
    const int c0 = 65536, c1 = c0 + 32768, c2 = c1 + 16384,
              c3 = c2 + 32768, c4 = c3 + 32768, c5 = c4 + 65536;
    if (id >= c5) return;
    const float* s; u16* d; int off;
    if      (id < c0) { s = s0; d = d0; off = id; }
    else if (id < c1) { s = s1; d = d1; off = id - c0; }
    else if (id < c2) { s = s2; d = d2; off = id - c1; }
    else if (id < c3) { s = s3; d = d3; off = id - c2; }
    else if (id < c4) { s = s4; d = d4; off = id - c3; }
    else              { s = s5; d = d5; off = id - c4; }
    float4 v = ((const float4*)s)[off];
    s4v p; p[0] = f2bf(v.x); p[1] = f2bf(v.y); p[2] = f2bf(v.z); p[3] = f2bf(v.w);
    ((s4v*)d)[off] = p;
}

// ---------------------------------------------------------------------------
// x [b][512][2304] fp32  ->  xT [b][2304][512] bf16  (LDS-tiled transpose)
// ---------------------------------------------------------------------------
__global__ __launch_bounds__(256) void transpose_x(const float* __restrict__ X,
                                                   u16* __restrict__ XT)
{
    __shared__ float tile[64][65];
    const int n0 = blockIdx.x * 64, c0 = blockIdx.y * 64, b = blockIdx.z;
    const float* src = X + (long)b * 512 * N_SP;
    u16* dst = XT + (long)b * N_SP * 512;
    const int t = threadIdx.x;
    #pragma unroll
    for (int it = 0; it < 16; ++it) {
        int id = t + 256 * it;
        int cl = id >> 6, nl = id & 63;
        tile[cl][nl] = src[(long)(c0 + cl) * N_SP + n0 + nl];
    }
    __syncthreads();
    #pragma unroll
    for (int it = 0; it < 16; ++it) {
        int id = t + 256 * it;
        int nl = id >> 6, cl = id & 63;
        dst[(long)(n0 + nl) * 512 + c0 + cl] = f2bf(tile[cl][nl]);
    }
}

// ---------------------------------------------------------------------------
// MFMA GEMM computing Y^T[n][o] = act((X^T W^T)*S + B) (+Res), all bf16.
//   A-operand = X^T rows (k-contiguous), B-operand = W rows (k-contiguous).
//   mfma(A,B): C/D lane holds [n = 4g+r][o = li]  (verified mapping).
// Tile: 128(n) x 64(o), BK=32, 256 thr = 4 waves in 2x2, wave = 64n x 32o.
// ASRC: 0 = A1/A2 are [n][k] (two-source concat via K1); 1 = A1 is [b][K][2304].
// OMODE: 0 = Y^T bf16 [n][sO]; 1 = normal bf16 [b][Mtot][2304]; 2 = normal f32.
// ---------------------------------------------------------------------------
template <int ASRC, int OMODE>
__global__ __launch_bounds__(256) void mfma_gemm(
    const u16* __restrict__ A1, const u16* __restrict__ A2, int K1,
    int sA1, int sA2, int K,
    const u16* __restrict__ W,
    const float* __restrict__ S, const float* __restrict__ Bi,
    const u16* __restrict__ Res, int sR,
    void* __restrict__ OutP, int sO, int Mtot,
    int act)
{
    __shared__ u16 Al[128][40];
    __shared__ u16 Bl[64][40];
    const int t  = threadIdx.x;
    const int n0 = blockIdx.x * 128;
    const int o0 = blockIdx.y * 64;
    const int lane = t & 63, w = t >> 6;
    const int wn = (w & 1) * 64, wo = (w >> 1) * 32;
    const int li = lane & 15, g = lane >> 4;

    const int b_blk = n0 / N_SP;           // batch of this n-tile (tile never crosses)
    const int n_in0 = n0 - b_blk * N_SP;
    const long abase = (long)b_blk * (long)K * N_SP;   // ASRC==1 base

    // staging assignments: A 512 chunks (2/thread), B 256 chunks (1/thread)
    const int an0 = t >> 2,          ac0 = (t & 3) * 8;
    const int an1 = (t + 256) >> 2,  ac1 = ac0;
    const int bo  = t >> 2,          bc  = (t & 3) * 8;

    f32x4 acc[4][2];
    #pragma unroll
    for (int fm = 0; fm < 4; ++fm)
        #pragma unroll
        for (int fn = 0; fn < 2; ++fn) acc[fm][fn] = f32x4{0.f, 0.f, 0.f, 0.f};

    // ---- chunk loaders ----
    auto ldA = [&](int nl, int k) -> u16x8 {
        if (ASRC) {
            u16x8 r;
            const u16* p = A1 + abase + (long)k * N_SP + n_in0 + nl;
            #pragma unroll
            for (int u = 0; u < 8; ++u) r[u] = p[(long)u * N_SP];
            return r;
        }
        if (k < K1) return *(const u16x8*)(A1 + (long)(n0 + nl) * sA1 + k);
        return *(const u16x8*)(A2 + (long)(n0 + nl) * sA2 + (k - K1));
    };

    u16x8 pa0 = ldA(an0, ac0);
    u16x8 pa1 = ldA(an1, ac1);
    u16x8 pb  = *(const u16x8*)(W + (long)(o0 + bo) * K + bc);

    for (int k0 = 0; k0 < K; k0 += 32) {
        __syncthreads();
        *(u16x8*)&Al[an0][ac0] = pa0;
        *(u16x8*)&Al[an1][ac1] = pa1;
        *(u16x8*)&Bl[bo][bc]   = pb;
        if (k0 + 32 < K) {
            pa0 = ldA(an0, k0 + 32 + ac0);
            pa1 = ldA(an1, k0 + 32 + ac1);
            pb  = *(const u16x8*)(W + (long)(o0 + bo) * K + k0 + 32 + bc);
        }
        __syncthreads();

        s8v af[4], bfv[2];
        #pragma unroll
        for (int fm = 0; fm < 4; ++fm)
            af[fm] = *(const s8v*)&Al[wn + fm * 16 + li][8 * g];
        #pragma unroll
        for (int fn = 0; fn < 2; ++fn)
            bfv[fn] = *(const s8v*)&Bl[wo + fn * 16 + li][8 * g];
        #pragma unroll
        for (int fm = 0; fm < 4; ++fm)
            #pragma unroll
            for (int fn = 0; fn < 2; ++fn)
                acc[fm][fn] = __builtin_amdgcn_mfma_f32_16x16x32_bf16(
                    af[fm], bfv[fn], acc[fm][fn], 0, 0, 0);
    }

    // ---- epilogue ----
    #pragma unroll
    for (int fn = 0; fn < 2; ++fn) {
        const int o = o0 + wo + fn * 16 + li;
        const float sc = S[o], bi = Bi[o];
        #pragma unroll
        for (int fm = 0; fm < 4; ++fm) {
            const int nb  = n0 + wn + fm * 16 + 4 * g;       // global n of r=0
            const int nib = n_in0 + wn + fm * 16 + 4 * g;    // in-batch n
            float y[4];
            #pragma unroll
            for (int r = 0; r < 4; ++r) {
                float v = acc[fm][fn][r] * sc + bi;
                if (act) v = v / (1.f + expf(-v));
                y[r] = v;
            }
            if (Res) {
                #pragma unroll
                for (int r = 0; r < 4; ++r)
                    y[r] += bf2f(Res[(long)(nb + r) * sR + o]);
            }
            if (OMODE == 0) {
                u16* O = (u16*)OutP;
                #pragma unroll
                for (int r = 0; r < 4; ++r)
                    O[(long)(nb + r) * sO + o] = (u16)f2bf(y[r]);
            } else if (OMODE == 1) {
                u16* O = (u16*)OutP + (long)b_blk * Mtot * N_SP + (long)o * N_SP + nib;
                s4v pk;
                #pragma unroll
                for (int r = 0; r < 4; ++r) pk[r] = f2bf(y[r]);
                *(s4v*)O = pk;
            } else {
                float* O = (float*)OutP + (long)b_blk * Mtot * N_SP + (long)o * N_SP + nib;
                float4 pk = make_float4(y[0], y[1], y[2], y[3]);
                *(float4*)O = pk;
            }
        }
    }
}

// ---------------------------------------------------------------------------
// MFMA flash attention (bf16 I/O). Block = 4 waves, one (b,h) x 64 queries.
// ---------------------------------------------------------------------------
__global__ __launch_bounds__(256) void attn_mfma(const u16* __restrict__ qkv,
                                                 u16* __restrict__ outp)
{
    const int N = N_SP;
    __shared__ u16 Klds[64][40];   // [j][d], 80B rows (16B aligned)
    __shared__ u16 Vlds[64][72];   // [d][j], 144B rows (16B aligned)

    const int i0 = blockIdx.x * 64;
    const int bh = blockIdx.y;
    const int b = bh >> 2, h = bh & 3;
    const int t = threadIdx.x;
    const int w = t >> 6;
    const int lane = t & 63;
    const int li = lane & 15;
    const int g  = lane >> 4;
    const float qscale = 0.17677669529663687f * 1.4426950408889634f;

    const u16* qp = qkv + ((long)b * 512 + (long)h * 128) * N;
    const u16* kp = qp + 32L * N;
    const u16* vp = qp + 64L * N;

    const int i = i0 + w * 16 + li;

    s8v qf;
    #pragma unroll
    for (int r = 0; r < 8; ++r)
        qf[r] = f2bf(bf2f(qp[(long)(8 * g + r) * N + i]) * qscale);

    f32x4 oacc[4];
    #pragma unroll
    for (int dt = 0; dt < 4; ++dt) oacc[dt] = f32x4{0.f, 0.f, 0.f, 0.f};
    float m_run = -1e30f, l_run = 0.f;

    const int kd  = t >> 3;            // 0..31
    const int kjb = (t & 7) * 8;       // 0..56
    const int vd  = t >> 2;            // 0..63
    const int vjb = (t & 3) * 16;      // 0..48
    u16x8 kr, vr0, vr1;
    kr  = *(const u16x8*)(kp + (long)kd * N + kjb);
    vr0 = *(const u16x8*)(vp + (long)vd * N + vjb);
    vr1 = *(const u16x8*)(vp + (long)vd * N + vjb + 8);

    for (int j0 = 0; j0 < N; j0 += 64) {
        __syncthreads();
        #pragma unroll
        for (int u = 0; u < 8; ++u) Klds[kjb + u][kd] = kr[u];
        *(u16x8*)&Vlds[vd][vjb]     = vr0;
        *(u16x8*)&Vlds[vd][vjb + 8] = vr1;
        if (j0 + 64 < N) {
            kr  = *(const u16x8*)(kp + (long)kd * N + (j0 + 64) + kjb);
            vr0 = *(const u16x8*)(vp + (long)vd * N + (j0 + 64) + vjb);
            vr1 = *(const u16x8*)(vp + (long)vd * N + (j0 + 64) + vjb + 8);
        }
        __syncthreads();

        // QK^T swapped: lane holds S[j = js*16 + 4g + r][i], log2-domain
        f32x4 sacc[4];
        #pragma unroll
        for (int js = 0; js < 4; ++js) {
            s8v kf = *(const s8v*)&Klds[js * 16 + li][8 * g];
            f32x4 z = f32x4{0.f, 0.f, 0.f, 0.f};
            sacc[js] = __builtin_amdgcn_mfma_f32_16x16x32_bf16(kf, qf, z, 0, 0, 0);
        }

        float tm = -1e30f;
        #pragma unroll
        for (int js = 0; js < 4; ++js)
            #pragma unroll
            for (int r = 0; r < 4; ++r) tm = fmaxf(tm, sacc[js][r]);
        tm = fmaxf(tm, __shfl_xor(tm, 16, 64));
        tm = fmaxf(tm, __shfl_xor(tm, 32, 64));
        float mnew = fmaxf(m_run, tm);
        float scl  = exp2f(m_run - mnew);
        float pl[4][4];
        float ts = 0.f;
        #pragma unroll
        for (int js = 0; js < 4; ++js)
            #pragma unroll
            for (int r = 0; r < 4; ++r) {
                float p = exp2f(sacc[js][r] - mnew);
                pl[js][r] = p;
                ts += p;
            }
        ts += __shfl_xor(ts, 16, 64);
        ts += __shfl_xor(ts, 32, 64);
        l_run = l_run * scl + ts;
        m_run = mnew;
        #pragma unroll
        for (int dt = 0; dt < 4; ++dt) oacc[dt] *= scl;

        // PV with k-permutation matching P's register layout
        #pragma unroll
        for (int ks = 0; ks < 2; ++ks) {
            s8v pf;
            #pragma unroll
            for (int r = 0; r < 4; ++r) {
                pf[r]     = f2bf(pl[2 * ks][r]);
                pf[4 + r] = f2bf(pl[2 * ks + 1][r]);
            }
            #pragma unroll
            for (int dt = 0; dt < 4; ++dt) {
                int d = dt * 16 + li;
                s4v lo = *(const s4v*)&Vlds[d][32 * ks + 4 * g];
                s4v hi = *(const s4v*)&Vlds[d][32 * ks + 16 + 4 * g];
                s8v vf = __builtin_shufflevector(lo, hi, 0, 1, 2, 3, 4, 5, 6, 7);
                oacc[dt] = __builtin_amdgcn_mfma_f32_16x16x32_bf16(vf, pf, oacc[dt], 0, 0, 0);
            }
        }
    }

    float inv = 1.f / l_run;
    long obase = ((long)b * 256 + (long)h * 64) * N + i;
    #pragma unroll
    for (int dt = 0; dt < 4; ++dt)
        #pragma unroll
        for (int r = 0; r < 4; ++r)
            outp[obase + (long)(dt * 16 + 4 * g + r) * N] = (u16)f2bf(oacc[dt][r] * inv);
}

// ---------------------------------------------------------------------------
// Depthwise 3x3 on v (bf16 qkv, channel remap), *s+b, RMW into attnbuf (bf16).
// ---------------------------------------------------------------------------
__global__ __launch_bounds__(256) void dwpe_kernel(const u16* __restrict__ qkv,
    const float* __restrict__ pw, const float* __restrict__ ps,
    const float* __restrict__ pb, u16* __restrict__ attnbuf)
{
    const int N = N_SP;
    int bc = blockIdx.x;
    int b = bc >> 8, c = bc & 255;
    int ch = ((c >> 6) * 128) + 64 + (c & 63);
    const u16* src = qkv + (long)b * 512 * N + (long)ch * N;
    float w[9];
    #pragma unroll
    for (int k = 0; k < 9; ++k) w[k] = pw[c * 9 + k];
    float sc = ps[c], bi = pb[c];
    u16* dst = attnbuf + (long)b * 256 * N + (long)c * N;

    for (int p = threadIdx.x; p < N; p += 256) {
        int y = p / HW, x = p - y * HW;
        float s = 0.f;
        #pragma unroll
        for (int dy = -1; dy <= 1; ++dy) {
            int yy = y + dy;
            if (yy < 0 || yy >= HW) continue;
            #pragma unroll
            for (int dx = -1; dx <= 1; ++dx) {
                int xx = x + dx;
                if (xx < 0 || xx >= HW) continue;
                s += w[(dy + 1) * 3 + (dx + 1)] * bf2f(src[yy * HW + xx]);
            }
        }
        dst[p] = (u16)f2bf(bf2f(dst[p]) + s * sc + bi);
    }
}

// ---------------------------------------------------------------------------
extern "C" void kernel_launch(void* const* d_in, const int* in_sizes, int n_in,
                              void* d_out, int out_size, void* d_ws, size_t ws_size,
                              hipStream_t stream)
{
    const long N = N_SP;
    const float* x      = (const float*)d_in[0];
    const float* cv1_w  = (const float*)d_in[1];
    const float* cv1_s  = (const float*)d_in[2];
    const float* cv1_b  = (const float*)d_in[3];
    const float* qkv_w  = (const float*)d_in[4];
    const float* qkv_s  = (const float*)d_in[5];
    const float* qkv_b  = (const float*)d_in[6];
    const float* pe_w   = (const float*)d_in[7];
    const float* pe_s   = (const float*)d_in[8];
    const float* pe_b   = (const float*)d_in[9];
    const float* proj_w = (const float*)d_in[10];
    const float* proj_s = (const float*)d_in[11];
    const float* proj_b = (const float*)d_in[12];
    const float* ffn1_w = (const float*)d_in[13];
    const float* ffn1_s = (const float*)d_in[14];
    const float* ffn1_b = (const float*)d_in[15];
    const float* ffn2_w = (const float*)d_in[16];
    const float* ffn2_s = (const float*)d_in[17];
    const float* ffn2_b = (const float*)d_in[18];
    const float* cv2_w  = (const float*)d_in[19];
    const float* cv2_s  = (const float*)d_in[20];
    const float* cv2_b  = (const float*)d_in[21];
    float* out = (float*)d_out;

    // workspace (all bf16)
    u16* ws = (u16*)d_ws;
    u16* xT      = ws;                       // [4][2304][512]
    u16* abT     = xT      + 4L * N * 512;   // [4][2304][512]
    u16* qkvb    = abT     + 4L * N * 512;   // [4][512][2304]
    u16* attnbuf = qkvb    + 4L * N * 512;   // [4][256][2304]
    u16* bb2T    = attnbuf + 4L * N * 256;   // [4][2304][256]
    u16* fT      = bb2T    + 4L * N * 256;   // [4][2304][512]
    u16* bb3T    = fT      + 4L * N * 512;   // [4][2304][256]
    u16* w_cv1   = bb3T    + 4L * N * 256;   // 512*512
    u16* w_qkv   = w_cv1   + 512L * 512;     // 512*256
    u16* w_proj  = w_qkv   + 512L * 256;     // 256*256
    u16* w_ffn1  = w_proj  + 256L * 256;     // 512*256
    u16* w_ffn2  = w_ffn1  + 512L * 256;     // 256*512
    u16* w_cv2   = w_ffn2  + 256L * 512;     // 512*512

    dim3 blk(256);
    const int BIGK = 1 << 28;

    // 0a. weights -> bf16
    cvt_w<<<960, blk, 0, stream>>>(cv1_w, qkv_w, proj_w, ffn1_w, ffn2_w, cv2_w,
                                   w_cv1, w_qkv, w_proj, w_ffn1, w_ffn2, w_cv2);
    // 0b. x -> xT bf16
    transpose_x<<<dim3(36, 8, 4), blk, 0, stream>>>(x, xT);

    // 1. abT = silu(cv1(x))^T
    mfma_gemm<0, 0><<<dim3(72, 8), blk, 0, stream>>>(
        xT, nullptr, BIGK, 512, 0, 512, w_cv1, cv1_s, cv1_b,
        nullptr, 0, abT, 512, 512, 1);

    // 2. qkvb = conv(bb) normal orientation [b][512][N]
    mfma_gemm<0, 1><<<dim3(72, 8), blk, 0, stream>>>(
        abT + 256, nullptr, BIGK, 512, 0, 256, w_qkv, qkv_s, qkv_b,
        nullptr, 0, qkvb, 0, 512, 0);

    // 3. attention core -> attnbuf [b][256][N]
    attn_mfma<<<dim3(36, 16), blk, 0, stream>>>(qkvb, attnbuf);

    // 4. attnbuf += dwconv3x3(v)*s+b
    dwpe_kernel<<<dim3(1024), blk, 0, stream>>>(qkvb, pe_w, pe_s, pe_b, attnbuf);

    // 5. bb2T = bb^T + proj(attnbuf)^T   (A transpose-staged from [ch][n])
    mfma_gemm<1, 0><<<dim3(72, 4), blk, 0, stream>>>(
        attnbuf, nullptr, BIGK, 0, 0, 256, w_proj, proj_s, proj_b,
        abT + 256, 512, bb2T, 256, 256, 0);

    // 6. fT = silu(ffn1(bb2))^T
    mfma_gemm<0, 0><<<dim3(72, 8), blk, 0, stream>>>(
        bb2T, nullptr, BIGK, 256, 0, 256, w_ffn1, ffn1_s, ffn1_b,
        nullptr, 0, fT, 512, 512, 1);

    // 7. bb3T = bb2T + ffn2(f)^T
    mfma_gemm<0, 0><<<dim3(72, 4), blk, 0, stream>>>(
        fT, nullptr, BIGK, 512, 0, 512, w_ffn2, ffn2_s, ffn2_b,
        bb2T, 256, bb3T, 256, 256, 0);

    // 8. out = silu(cv2(concat(a, bb3)))  fp32 normal [b][512][N]
    mfma_gemm<0, 2><<<dim3(72, 8), blk, 0, stream>>>(
        abT, bb3T, 256, 512, 256, 512, w_cv2, cv2_s, cv2_b,
        nullptr, 0, out, 0, 512, 1);
}

// Round 5
// 171.359 us; speedup vs baseline: 41.5511x; 1.2110x over previous
//
#include <hip/hip_runtime.h>
#include <math.h>

#define N_SP 2304   // 48*48 spatial
#define HW 48

typedef unsigned short u16;
typedef short s8v  __attribute__((ext_vector_type(8)));   // bf16x8 (MFMA operand)
typedef short s4v  __attribute__((ext_vector_type(4)));   // bf16x4
typedef u16   u16x8 __attribute__((ext_vector_type(8)));
typedef float f32x4 __attribute__((ext_vector_type(4)));

__device__ __forceinline__ short f2bf(float x) {
    unsigned u = __float_as_uint(x);
    u += 0x7FFFu + ((u >> 16) & 1u);
    return (short)(u >> 16);
}
__device__ __forceinline__ float bf2f(u16 u) {
    return __uint_as_float((unsigned)u << 16);
}

// ---------------------------------------------------------------------------
// Weight fp32 -> bf16 (all six weight matrices in one launch, float4 chunks)
// ---------------------------------------------------------------------------
__global__ __launch_bounds__(256) void cvt_w(
    const float* __restrict__ s0, const float* __restrict__ s1,
    const float* __restrict__ s2, const float* __restrict__ s3,
    const float* __restrict__ s4, const float* __restrict__ s5,
    u16* __restrict__ d0, u16* __restrict__ d1, u16* __restrict__ d2,
    u16* __restrict__ d3, u16* __restrict__ d4, u16* __restrict__ d5)
{
    int id = blockIdx.x * 256 + threadIdx.x;   // float4 index
    const int c0 = 65536, c1 = c0 + 32768, c2 = c1 + 16384,
              c3 = c2 + 32768, c4 = c3 + 32768, c5 = c4 + 65536;
    if (id >= c5) return;
    const float* s; u16* d; int off;
    if      (id < c0) { s = s0; d = d0; off = id; }
    else if (id < c1) { s = s1; d = d1; off = id - c0; }
    else if (id < c2) { s = s2; d = d2; off = id - c1; }
    else if (id < c3) { s = s3; d = d3; off = id - c2; }
    else if (id < c4) { s = s4; d = d4; off = id - c3; }
    else              { s = s5; d = d5; off = id - c4; }
    float4 v = ((const float4*)s)[off];
    s4v p; p[0] = f2bf(v.x); p[1] = f2bf(v.y); p[2] = f2bf(v.z); p[3] = f2bf(v.w);
    ((s4v*)d)[off] = p;
}

// ---------------------------------------------------------------------------
// x [b][512][2304] fp32  ->  xT [b][2304][512] bf16  (LDS-tiled transpose)
// ---------------------------------------------------------------------------
__global__ __launch_bounds__(256) void transpose_x(const float* __restrict__ X,
                                                   u16* __restrict__ XT)
{
    __shared__ float tile[64][65];
    const int n0 = blockIdx.x * 64, c0 = blockIdx.y * 64, b = blockIdx.z;
    const float* src = X + (long)b * 512 * N_SP;
    u16* dst = XT + (long)b * N_SP * 512;
    const int t = threadIdx.x;
    #pragma unroll
    for (int it = 0; it < 16; ++it) {
        int id = t + 256 * it;
        int cl = id >> 6, nl = id & 63;
        tile[cl][nl] = src[(long)(c0 + cl) * N_SP + n0 + nl];
    }
    __syncthreads();
    #pragma unroll
    for (int it = 0; it < 16; ++it) {
        int id = t + 256 * it;
        int nl = id >> 6, cl = id & 63;
        dst[(long)(n0 + nl) * 512 + c0 + cl] = f2bf(tile[cl][nl]);
    }
}

// ---------------------------------------------------------------------------
// MFMA GEMM: Y^T[n][o] = act((X^T W^T)*S + B) (+Res), bf16, 64x64 tile, BK=32.
// 4 waves 2x2, wave = 32n x 32o (2x2 fragments). A rows k-contiguous from
// A1 (k<K1) / A2 (k>=K1, two-source concat). OMODE: 0 = Y^T bf16 [n][sO];
// 1 = normal bf16 [b][Mtot][2304]; 2 = normal f32 [b][Mtot][2304].
// ---------------------------------------------------------------------------
template <int OMODE>
__global__ __launch_bounds__(256) void mfma_gemm(
    const u16* __restrict__ A1, const u16* __restrict__ A2, int K1,
    int sA1, int sA2, int K,
    const u16* __restrict__ W,
    const float* __restrict__ S, const float* __restrict__ Bi,
    const u16* __restrict__ Res, int sR,
    void* __restrict__ OutP, int sO, int Mtot,
    int act)
{
    __shared__ u16 Al[64][40];
    __shared__ u16 Bl[64][40];
    const int t  = threadIdx.x;
    const int n0 = blockIdx.x * 64;
    const int o0 = blockIdx.y * 64;
    const int lane = t & 63, w = t >> 6;
    const int wn = (w & 1) * 32, wo = (w >> 1) * 32;
    const int li = lane & 15, g = lane >> 4;

    const int b_blk = n0 / N_SP;           // 2304 % 64 == 0: tile never crosses batch
    const int n_in0 = n0 - b_blk * N_SP;

    const int ar = t >> 2, ac = (t & 3) * 8;   // staging row / k-offset

    f32x4 acc[2][2];
    #pragma unroll
    for (int fm = 0; fm < 2; ++fm)
        #pragma unroll
        for (int fn = 0; fn < 2; ++fn) acc[fm][fn] = f32x4{0.f, 0.f, 0.f, 0.f};

    auto ldA = [&](int k) -> u16x8 {
        int kk = k + ac;
        if (kk < K1) return *(const u16x8*)(A1 + (long)(n0 + ar) * sA1 + kk);
        return *(const u16x8*)(A2 + (long)(n0 + ar) * sA2 + (kk - K1));
    };

    u16x8 pa = ldA(0);
    u16x8 pb = *(const u16x8*)(W + (long)(o0 + ar) * K + ac);

    for (int k0 = 0; k0 < K; k0 += 32) {
        __syncthreads();
        *(u16x8*)&Al[ar][ac] = pa;
        *(u16x8*)&Bl[ar][ac] = pb;
        if (k0 + 32 < K) {
            pa = ldA(k0 + 32);
            pb = *(const u16x8*)(W + (long)(o0 + ar) * K + k0 + 32 + ac);
        }
        __syncthreads();

        s8v af[2], bfv[2];
        #pragma unroll
        for (int fm = 0; fm < 2; ++fm)
            af[fm] = *(const s8v*)&Al[wn + fm * 16 + li][8 * g];
        #pragma unroll
        for (int fn = 0; fn < 2; ++fn)
            bfv[fn] = *(const s8v*)&Bl[wo + fn * 16 + li][8 * g];
        #pragma unroll
        for (int fm = 0; fm < 2; ++fm)
            #pragma unroll
            for (int fn = 0; fn < 2; ++fn)
                acc[fm][fn] = __builtin_amdgcn_mfma_f32_16x16x32_bf16(
                    af[fm], bfv[fn], acc[fm][fn], 0, 0, 0);
    }

    #pragma unroll
    for (int fn = 0; fn < 2; ++fn) {
        const int o = o0 + wo + fn * 16 + li;
        const float sc = S[o], bi = Bi[o];
        #pragma unroll
        for (int fm = 0; fm < 2; ++fm) {
            const int nb  = n0 + wn + fm * 16 + 4 * g;
            const int nib = n_in0 + wn + fm * 16 + 4 * g;
            float y[4];
            #pragma unroll
            for (int r = 0; r < 4; ++r) {
                float v = acc[fm][fn][r] * sc + bi;
                if (act) v = v / (1.f + expf(-v));
                y[r] = v;
            }
            if (Res) {
                #pragma unroll
                for (int r = 0; r < 4; ++r)
                    y[r] += bf2f(Res[(long)(nb + r) * sR + o]);
            }
            if (OMODE == 0) {
                u16* O = (u16*)OutP;
                #pragma unroll
                for (int r = 0; r < 4; ++r)
                    O[(long)(nb + r) * sO + o] = (u16)f2bf(y[r]);
            } else if (OMODE == 1) {
                u16* O = (u16*)OutP + (long)b_blk * Mtot * N_SP + (long)o * N_SP + nib;
                s4v pk;
                #pragma unroll
                for (int r = 0; r < 4; ++r) pk[r] = f2bf(y[r]);
                *(s4v*)O = pk;
            } else {
                float* O = (float*)OutP + (long)b_blk * Mtot * N_SP + (long)o * N_SP + nib;
                *(float4*)O = make_float4(y[0], y[1], y[2], y[3]);
            }
        }
    }
}

// ---------------------------------------------------------------------------
// MFMA flash attention, split-j x4. Block = 4 waves, one (b,h) x 64 queries x
// one 576-j chunk. Writes unnormalized partial O (bf16) + per-(i,chunk) m,l.
// K staging: thread loads 8 d's for one j (coalesced 128B rows per load),
// writes one u16x8 per j-row -> conflict-free LDS writes.
// ---------------------------------------------------------------------------
__global__ __launch_bounds__(256) void attn_mfma(const u16* __restrict__ qkv,
    u16* __restrict__ Opart, float* __restrict__ mpart, float* __restrict__ lpart)
{
    const int N = N_SP;
    __shared__ u16 Klds[64][40];   // [j][d], 80B rows (16B aligned)
    __shared__ u16 Vlds[64][72];   // [d][j], 144B rows (16B aligned)

    const int i0 = blockIdx.x * 64;
    const int bh = blockIdx.y;
    const int z  = blockIdx.z;      // j-chunk
    const int b = bh >> 2, h = bh & 3;
    const int t = threadIdx.x;
    const int w = t >> 6;
    const int lane = t & 63;
    const int li = lane & 15;
    const int g  = lane >> 4;
    const float qscale = 0.17677669529663687f * 1.4426950408889634f;

    const u16* qp = qkv + ((long)b * 512 + (long)h * 128) * N;
    const u16* kp = qp + 32L * N;
    const u16* vp = qp + 64L * N;

    const int i = i0 + w * 16 + li;

    s8v qf;
    #pragma unroll
    for (int r = 0; r < 8; ++r)
        qf[r] = f2bf(bf2f(qp[(long)(8 * g + r) * N + i]) * qscale);

    f32x4 oacc[4];
    #pragma unroll
    for (int dt = 0; dt < 4; ++dt) oacc[dt] = f32x4{0.f, 0.f, 0.f, 0.f};
    float m_run = -1e30f, l_run = 0.f;

    // staging assignments
    const int kj  = lane;              // j within tile
    const int kd0 = w * 8;             // 8 d's per thread
    const int vd  = t >> 2;            // 0..63
    const int vjb = (t & 3) * 16;      // 0..48

    const int jbase = z * 576;
    u16x8 kr, vr0, vr1;
    {
        const u16* kpp = kp + jbase + kj;
        #pragma unroll
        for (int u = 0; u < 8; ++u) kr[u] = kpp[(long)(kd0 + u) * N];
        vr0 = *(const u16x8*)(vp + (long)vd * N + jbase + vjb);
        vr1 = *(const u16x8*)(vp + (long)vd * N + jbase + vjb + 8);
    }

    for (int j0 = jbase; j0 < jbase + 576; j0 += 64) {
        __syncthreads();
        *(u16x8*)&Klds[kj][kd0]     = kr;
        *(u16x8*)&Vlds[vd][vjb]     = vr0;
        *(u16x8*)&Vlds[vd][vjb + 8] = vr1;
        if (j0 + 64 < jbase + 576) {
            const u16* kpp = kp + (j0 + 64) + kj;
            #pragma unroll
            for (int u = 0; u < 8; ++u) kr[u] = kpp[(long)(kd0 + u) * N];
            vr0 = *(const u16x8*)(vp + (long)vd * N + (j0 + 64) + vjb);
            vr1 = *(const u16x8*)(vp + (long)vd * N + (j0 + 64) + vjb + 8);
        }
        __syncthreads();

        // QK^T swapped: lane holds S[j = js*16 + 4g + r][i], log2-domain
        f32x4 sacc[4];
        #pragma unroll
        for (int js = 0; js < 4; ++js) {
            s8v kf = *(const s8v*)&Klds[js * 16 + li][8 * g];
            f32x4 zz = f32x4{0.f, 0.f, 0.f, 0.f};
            sacc[js] = __builtin_amdgcn_mfma_f32_16x16x32_bf16(kf, qf, zz, 0, 0, 0);
        }

        float tm = -1e30f;
        #pragma unroll
        for (int js = 0; js < 4; ++js)
            #pragma unroll
            for (int r = 0; r < 4; ++r) tm = fmaxf(tm, sacc[js][r]);
        tm = fmaxf(tm, __shfl_xor(tm, 16, 64));
        tm = fmaxf(tm, __shfl_xor(tm, 32, 64));
        // defer-max (T13): rescale only when some row grew by >8 (log2)
        if (__any(tm > m_run + 8.f)) {
            float mnew = fmaxf(m_run, tm);
            float scl  = exp2f(m_run - mnew);
            l_run *= scl;
            #pragma unroll
            for (int dt = 0; dt < 4; ++dt) oacc[dt] *= scl;
            m_run = mnew;
        }
        float pl[4][4];
        float ts = 0.f;
        #pragma unroll
        for (int js = 0; js < 4; ++js)
            #pragma unroll
            for (int r = 0; r < 4; ++r) {
                float p = exp2f(sacc[js][r] - m_run);
                pl[js][r] = p;
                ts += p;
            }
        ts += __shfl_xor(ts, 16, 64);
        ts += __shfl_xor(ts, 32, 64);
        l_run += ts;

        // PV with k-permutation matching P's register layout
        #pragma unroll
        for (int ks = 0; ks < 2; ++ks) {
            s8v pf;
            #pragma unroll
            for (int r = 0; r < 4; ++r) {
                pf[r]     = f2bf(pl[2 * ks][r]);
                pf[4 + r] = f2bf(pl[2 * ks + 1][r]);
            }
            #pragma unroll
            for (int dt = 0; dt < 4; ++dt) {
                int d = dt * 16 + li;
                s4v lo = *(const s4v*)&Vlds[d][32 * ks + 4 * g];
                s4v hi = *(const s4v*)&Vlds[d][32 * ks + 16 + 4 * g];
                s8v vf = __builtin_shufflevector(lo, hi, 0, 1, 2, 3, 4, 5, 6, 7);
                oacc[dt] = __builtin_amdgcn_mfma_f32_16x16x32_bf16(vf, pf, oacc[dt], 0, 0, 0);
            }
        }
    }

    // epilogue: unnormalized partial O (bf16) + m,l per (i, chunk)
    const long cb = (long)(z * 16 + bh);
    #pragma unroll
    for (int dt = 0; dt < 4; ++dt)
        #pragma unroll
        for (int r = 0; r < 4; ++r)
            Opart[(cb * 64 + dt * 16 + 4 * g + r) * N + i] = (u16)f2bf(oacc[dt][r]);
    if (g == 0) {
        mpart[cb * N + i] = m_run;
        lpart[cb * N + i] = l_run;
    }
}

// ---------------------------------------------------------------------------
// Combine split-j partials + fused depthwise-3x3 PE on v; writes transposed
// attnT [b][n][256] (bf16) so proj's GEMM gets a k-contiguous A operand.
// ---------------------------------------------------------------------------
__global__ __launch_bounds__(256) void attn_combine(
    const u16* __restrict__ Opart, const float* __restrict__ mpart,
    const float* __restrict__ lpart, const u16* __restrict__ qkv,
    const float* __restrict__ pw, const float* __restrict__ ps,
    const float* __restrict__ pb, u16* __restrict__ attnT)
{
    const int N = N_SP;
    const int i0 = blockIdx.x * 64;
    const int bh = blockIdx.y;
    const int b = bh >> 2, h = bh & 3;
    const int t = threadIdx.x;
    const int il = t & 63, dq = t >> 6;
    const int d0 = dq * 16;
    const int i = i0 + il;

    // combine weights
    float mm[4], ll[4];
    #pragma unroll
    for (int c = 0; c < 4; ++c) {
        mm[c] = mpart[((long)(c * 16 + bh)) * N + i];
        ll[c] = lpart[((long)(c * 16 + bh)) * N + i];
    }
    float ms = fmaxf(fmaxf(mm[0], mm[1]), fmaxf(mm[2], mm[3]));
    float wc[4], lsum = 0.f;
    #pragma unroll
    for (int c = 0; c < 4; ++c) {
        wc[c] = exp2f(mm[c] - ms);
        lsum += wc[c] * ll[c];
    }
    float inv = 1.f / lsum;

    // PE geometry
    const int y = i / HW, x = i - (i / HW) * HW;
    const int y0ok = (y > 0), y1ok = (y < HW - 1);
    const int x0ok = (x > 0), x1ok = (x < HW - 1);
    const u16* vbase = qkv + ((long)b * 512 + (long)h * 128 + 64) * N;

    u16 ob[16];
    #pragma unroll
    for (int dd = 0; dd < 16; ++dd) {
        const int d = d0 + dd;
        const int cg = h * 64 + d;
        // attention combine
        float o = 0.f;
        #pragma unroll
        for (int c = 0; c < 4; ++c)
            o += wc[c] * bf2f(Opart[((long)(c * 16 + bh) * 64 + d) * N + i]);
        o *= inv;
        // depthwise 3x3 on v channel d (zero padding)
        const u16* src = vbase + (long)d * N;
        const float* w9 = pw + cg * 9;
        float s = 0.f;
        #pragma unroll
        for (int dy = -1; dy <= 1; ++dy) {
            if ((dy < 0 && !y0ok) || (dy > 0 && !y1ok)) continue;
            const u16* row = src + (y + dy) * HW;
            if (x0ok) s += w9[(dy + 1) * 3 + 0] * bf2f(row[x - 1]);
            s += w9[(dy + 1) * 3 + 1] * bf2f(row[x]);
            if (x1ok) s += w9[(dy + 1) * 3 + 2] * bf2f(row[x + 1]);
        }
        o += s * ps[cg] + pb[cg];
        ob[dd] = (u16)f2bf(o);
    }
    u16* dst = attnT + ((long)b * N + i) * 256 + h * 64 + d0;
    *(u16x8*)dst       = *(u16x8*)&ob[0];
    *(u16x8*)(dst + 8) = *(u16x8*)&ob[8];
}

// ---------------------------------------------------------------------------
extern "C" void kernel_launch(void* const* d_in, const int* in_sizes, int n_in,
                              void* d_out, int out_size, void* d_ws, size_t ws_size,
                              hipStream_t stream)
{
    const long N = N_SP;
    const float* x      = (const float*)d_in[0];
    const float* cv1_w  = (const float*)d_in[1];
    const float* cv1_s  = (const float*)d_in[2];
    const float* cv1_b  = (const float*)d_in[3];
    const float* qkv_w  = (const float*)d_in[4];
    const float* qkv_s  = (const float*)d_in[5];
    const float* qkv_b  = (const float*)d_in[6];
    const float* pe_w   = (const float*)d_in[7];
    const float* pe_s   = (const float*)d_in[8];
    const float* pe_b   = (const float*)d_in[9];
    const float* proj_w = (const float*)d_in[10];
    const float* proj_s = (const float*)d_in[11];
    const float* proj_b = (const float*)d_in[12];
    const float* ffn1_w = (const float*)d_in[13];
    const float* ffn1_s = (const float*)d_in[14];
    const float* ffn1_b = (const float*)d_in[15];
    const float* ffn2_w = (const float*)d_in[16];
    const float* ffn2_s = (const float*)d_in[17];
    const float* ffn2_b = (const float*)d_in[18];
    const float* cv2_w  = (const float*)d_in[19];
    const float* cv2_s  = (const float*)d_in[20];
    const float* cv2_b  = (const float*)d_in[21];
    float* out = (float*)d_out;

    u16* ws = (u16*)d_ws;
    u16* xT      = ws;                       // [4][2304][512]
    u16* abT     = xT      + 4L * N * 512;   // [4][2304][512]
    u16* qkvb    = abT     + 4L * N * 512;   // [4][512][2304]
    u16* attnT   = qkvb    + 4L * N * 512;   // [4][2304][256]
    u16* bb2T    = attnT   + 4L * N * 256;   // [4][2304][256]
    u16* fT      = bb2T    + 4L * N * 256;   // [4][2304][512]
    u16* bb3T    = fT      + 4L * N * 512;   // [4][2304][256]
    u16* w_cv1   = bb3T    + 4L * N * 256;   // 512*512
    u16* w_qkv   = w_cv1   + 512L * 512;
    u16* w_proj  = w_qkv   + 512L * 256;
    u16* w_ffn1  = w_proj  + 256L * 256;
    u16* w_ffn2  = w_ffn1  + 512L * 256;
    u16* w_cv2   = w_ffn2  + 256L * 512;
    u16* Opart   = w_cv2   + 512L * 512;     // [4][16][64][2304] bf16
    float* mpart = (float*)(Opart + 4L * 16 * 64 * N);   // [4][16][2304]
    float* lpart = mpart + 4L * 16 * N;

    dim3 blk(256);
    const int BIGK = 1 << 28;

    cvt_w<<<960, blk, 0, stream>>>(cv1_w, qkv_w, proj_w, ffn1_w, ffn2_w, cv2_w,
                                   w_cv1, w_qkv, w_proj, w_ffn1, w_ffn2, w_cv2);
    transpose_x<<<dim3(36, 8, 4), blk, 0, stream>>>(x, xT);

    // 1. abT = silu(cv1(x))^T
    mfma_gemm<0><<<dim3(144, 8), blk, 0, stream>>>(
        xT, nullptr, BIGK, 512, 0, 512, w_cv1, cv1_s, cv1_b,
        nullptr, 0, abT, 512, 512, 1);

    // 2. qkvb = conv(bb) normal orientation [b][512][N]
    mfma_gemm<1><<<dim3(144, 8), blk, 0, stream>>>(
        abT + 256, nullptr, BIGK, 512, 0, 256, w_qkv, qkv_s, qkv_b,
        nullptr, 0, qkvb, 0, 512, 0);

    // 3. attention partials (split-j x4)
    attn_mfma<<<dim3(36, 16, 4), blk, 0, stream>>>(qkvb, Opart, mpart, lpart);

    // 4. combine + fused PE -> attnT [b][n][256]
    attn_combine<<<dim3(36, 16), blk, 0, stream>>>(
        Opart, mpart, lpart, qkvb, pe_w, pe_s, pe_b, attnT);

    // 5. bb2T = bb^T + proj(attn)^T
    mfma_gemm<0><<<dim3(144, 4), blk, 0, stream>>>(
        attnT, nullptr, BIGK, 256, 0, 256, w_proj, proj_s, proj_b,
        abT + 256, 512, bb2T, 256, 256, 0);

    // 6. fT = silu(ffn1(bb2))^T
    mfma_gemm<0><<<dim3(144, 8), blk, 0, stream>>>(
        bb2T, nullptr, BIGK, 256, 0, 256, w_ffn1, ffn1_s, ffn1_b,
        nullptr, 0, fT, 512, 512, 1);

    // 7. bb3T = bb2T + ffn2(f)^T
    mfma_gemm<0><<<dim3(144, 4), blk, 0, stream>>>(
        fT, nullptr, BIGK, 512, 0, 512, w_ffn2, ffn2_s, ffn2_b,
        bb2T, 256, bb3T, 256, 256, 0);

    // 8. out = silu(cv2(concat(a, bb3)))  fp32 normal [b][512][N]
    mfma_gemm<2><<<dim3(144, 8), blk, 0, stream>>>(
        abT, bb3T, 256, 512, 256, 512, w_cv2, cv2_s, cv2_b,
        nullptr, 0, out, 0, 512, 1);
}

// Round 6
// 155.583 us; speedup vs baseline: 45.7642x; 1.1014x over previous
//
#include <hip/hip_runtime.h>
#include <math.h>

#define N_SP 2304   // 48*48 spatial
#define HW 48

typedef unsigned short u16;
typedef short s8v  __attribute__((ext_vector_type(8)));   // bf16x8 (MFMA operand)
typedef short s4v  __attribute__((ext_vector_type(4)));   // bf16x4
typedef u16   u16x8 __attribute__((ext_vector_type(8)));
typedef float f32x4 __attribute__((ext_vector_type(4)));
typedef unsigned u32x4 __attribute__((ext_vector_type(4)));

__device__ __forceinline__ short f2bf(float x) {
    unsigned u = __float_as_uint(x);
    u += 0x7FFFu + ((u >> 16) & 1u);
    return (short)(u >> 16);
}
__device__ __forceinline__ float bf2f(u16 u) {
    return __uint_as_float((unsigned)u << 16);
}
__device__ __forceinline__ float fexp2(float x) {      // raw v_exp_f32
    return __builtin_amdgcn_exp2f(x);
}
__device__ __forceinline__ float frcp(float x) {       // raw v_rcp_f32
    return __builtin_amdgcn_rcpf(x);
}
__device__ __forceinline__ float fsilu(float v) {
    return v * frcp(1.f + fexp2(-1.4426950408889634f * v));
}
__device__ __forceinline__ unsigned cvtpk(float lo, float hi) {  // 2xf32 -> packed bf16
    unsigned r;
    asm("v_cvt_pk_bf16_f32 %0, %1, %2" : "=v"(r) : "v"(lo), "v"(hi));
    return r;
}
__device__ __forceinline__ void gload16(const void* g, void* l) {
    __builtin_amdgcn_global_load_lds(
        (const __attribute__((address_space(1))) void*)g,
        (__attribute__((address_space(3))) void*)l, 16, 0, 0);
}

// ---------------------------------------------------------------------------
// Weight fp32 -> bf16 (all six weight matrices in one launch, float4 chunks)
// ---------------------------------------------------------------------------
__global__ __launch_bounds__(256) void cvt_w(
    const float* __restrict__ s0, const float* __restrict__ s1,
    const float* __restrict__ s2, const float* __restrict__ s3,
    const float* __restrict__ s4, const float* __restrict__ s5,
    u16* __restrict__ d0, u16* __restrict__ d1, u16* __restrict__ d2,
    u16* __restrict__ d3, u16* __restrict__ d4, u16* __restrict__ d5)
{
    int id = blockIdx.x * 256 + threadIdx.x;   // float4 index
    const int c0 = 65536, c1 = c0 + 32768, c2 = c1 + 16384,
              c3 = c2 + 32768, c4 = c3 + 32768, c5 = c4 + 65536;
    if (id >= c5) return;
    const float* s; u16* d; int off;
    if      (id < c0) { s = s0; d = d0; off = id; }
    else if (id < c1) { s = s1; d = d1; off = id - c0; }
    else if (id < c2) { s = s2; d = d2; off = id - c1; }
    else if (id < c3) { s = s3; d = d3; off = id - c2; }
    else if (id < c4) { s = s4; d = d4; off = id - c3; }
    else              { s = s5; d = d5; off = id - c4; }
    float4 v = ((const float4*)s)[off];
    s4v p; p[0] = f2bf(v.x); p[1] = f2bf(v.y); p[2] = f2bf(v.z); p[3] = f2bf(v.w);
    ((s4v*)d)[off] = p;
}

// ---------------------------------------------------------------------------
// x [b][512][2304] fp32  ->  xT [b][2304][512] bf16  (LDS-tiled transpose)
// ---------------------------------------------------------------------------
__global__ __launch_bounds__(256) void transpose_x(const float* __restrict__ X,
                                                   u16* __restrict__ XT)
{
    __shared__ float tile[64][65];
    const int n0 = blockIdx.x * 64, c0 = blockIdx.y * 64, b = blockIdx.z;
    const float* src = X + (long)b * 512 * N_SP;
    u16* dst = XT + (long)b * N_SP * 512;
    const int t = threadIdx.x;
    #pragma unroll
    for (int it = 0; it < 16; ++it) {
        int id = t + 256 * it;
        int cl = id >> 6, nl = id & 63;
        tile[cl][nl] = src[(long)(c0 + cl) * N_SP + n0 + nl];
    }
    __syncthreads();
    #pragma unroll
    for (int it = 0; it < 16; ++it) {
        int id = t + 256 * it;
        int nl = id >> 6, cl = id & 63;
        dst[(long)(n0 + nl) * 512 + c0 + cl] = f2bf(tile[cl][nl]);
    }
}

// ---------------------------------------------------------------------------
// MFMA GEMM: Y^T[n][o] = act((X^T W^T)*S + B) (+Res), bf16, 64x64 tile, BK=32.
// Pipeline: global_load_lds(16B) into double-buffered unpadded [64][32] LDS
// (b128 reads are at the 8/bank wave64 floor), ONE barrier per K-step; the
// next tile's loads stay in flight across the compute phase.
// OMODE: 0 = Y^T bf16 [n][sO]; 1 = normal bf16 [b][Mtot][2304]; 2 = f32.
// ---------------------------------------------------------------------------
template <int OMODE>
__global__ __launch_bounds__(256) void mfma_gemm(
    const u16* __restrict__ A1, const u16* __restrict__ A2, int K1,
    int sA1, int sA2, int K,
    const u16* __restrict__ W,
    const float* __restrict__ S, const float* __restrict__ Bi,
    const u16* __restrict__ Res, int sR,
    void* __restrict__ OutP, int sO, int Mtot,
    int act)
{
    __shared__ u16 Al[2][64][32];
    __shared__ u16 Bl[2][64][32];
    const int t  = threadIdx.x;
    const int n0 = blockIdx.x * 64;
    const int o0 = blockIdx.y * 64;
    const int lane = t & 63, w = t >> 6;
    const int wn = (w & 1) * 32, wo = (w >> 1) * 32;
    const int li = lane & 15, g = lane >> 4;

    const int b_blk = n0 / N_SP;           // 2304 % 64 == 0: tile never crosses batch
    const int n_in0 = n0 - b_blk * N_SP;

    const int sr = t >> 2, sc = (t & 3) * 8;   // this thread's 16B staging chunk

    f32x4 acc[2][2];
    #pragma unroll
    for (int fm = 0; fm < 2; ++fm)
        #pragma unroll
        for (int fn = 0; fn < 2; ++fn) acc[fm][fn] = f32x4{0.f, 0.f, 0.f, 0.f};

    // issue this K-step's staging loads (async, direct to LDS)
    auto issue = [&](int buf, int k0) {
        const int kk = k0 + sc;
        const u16* ga = (kk < K1) ? (A1 + (long)(n0 + sr) * sA1 + kk)
                                  : (A2 + (long)(n0 + sr) * sA2 + (kk - K1));
        gload16(ga, &Al[buf][w * 16][0]);
        gload16(W + (long)(o0 + sr) * K + k0 + sc, &Bl[buf][w * 16][0]);
    };

    issue(0, 0);
    int cur = 0;
    for (int k0 = 0; k0 < K; k0 += 32) {
        __syncthreads();                       // drains vmcnt -> buf[cur] ready
        if (k0 + 32 < K) issue(cur ^ 1, k0 + 32);   // in flight across compute
        s8v af[2], bfv[2];
        #pragma unroll
        for (int fm = 0; fm < 2; ++fm)
            af[fm] = *(const s8v*)&Al[cur][wn + fm * 16 + li][8 * g];
        #pragma unroll
        for (int fn = 0; fn < 2; ++fn)
            bfv[fn] = *(const s8v*)&Bl[cur][wo + fn * 16 + li][8 * g];
        #pragma unroll
        for (int fm = 0; fm < 2; ++fm)
            #pragma unroll
            for (int fn = 0; fn < 2; ++fn)
                acc[fm][fn] = __builtin_amdgcn_mfma_f32_16x16x32_bf16(
                    af[fm], bfv[fn], acc[fm][fn], 0, 0, 0);
        cur ^= 1;
    }

    #pragma unroll
    for (int fn = 0; fn < 2; ++fn) {
        const int o = o0 + wo + fn * 16 + li;
        const float sc2 = S[o], bi = Bi[o];
        #pragma unroll
        for (int fm = 0; fm < 2; ++fm) {
            const int nb  = n0 + wn + fm * 16 + 4 * g;
            const int nib = n_in0 + wn + fm * 16 + 4 * g;
            float y[4];
            #pragma unroll
            for (int r = 0; r < 4; ++r) {
                float v = acc[fm][fn][r] * sc2 + bi;
                if (act) v = fsilu(v);
                y[r] = v;
            }
            if (Res) {
                #pragma unroll
                for (int r = 0; r < 4; ++r)
                    y[r] += bf2f(Res[(long)(nb + r) * sR + o]);
            }
            if (OMODE == 0) {
                u16* O = (u16*)OutP;
                #pragma unroll
                for (int r = 0; r < 4; ++r)
                    O[(long)(nb + r) * sO + o] = (u16)f2bf(y[r]);
            } else if (OMODE == 1) {
                u16* O = (u16*)OutP + (long)b_blk * Mtot * N_SP + (long)o * N_SP + nib;
                s4v pk;
                #pragma unroll
                for (int r = 0; r < 4; ++r) pk[r] = f2bf(y[r]);
                *(s4v*)O = pk;
            } else {
                float* O = (float*)OutP + (long)b_blk * Mtot * N_SP + (long)o * N_SP + nib;
                *(float4*)O = make_float4(y[0], y[1], y[2], y[3]);
            }
        }
    }
}

// ---------------------------------------------------------------------------
// MFMA flash attention, split-j x4. Block = 4 waves, one (b,h) x 64 queries x
// one 576-j chunk. Unnormalized partial O (bf16) + per-(i,chunk) m,l.
// Hot path uses raw v_exp_f32 and v_cvt_pk_bf16_f32 (libm exp2f/software
// f2bf were the VALU bottleneck: 74% VALUBusy at R4).
// ---------------------------------------------------------------------------
__global__ __launch_bounds__(256) void attn_mfma(const u16* __restrict__ qkv,
    u16* __restrict__ Opart, float* __restrict__ mpart, float* __restrict__ lpart)
{
    const int N = N_SP;
    __shared__ u16 Klds[64][40];   // [j][d]
    __shared__ u16 Vlds[64][72];   // [d][j]

    const int i0 = blockIdx.x * 64;
    const int bh = blockIdx.y;
    const int z  = blockIdx.z;      // j-chunk
    const int b = bh >> 2, h = bh & 3;
    const int t = threadIdx.x;
    const int w = t >> 6;
    const int lane = t & 63;
    const int li = lane & 15;
    const int g  = lane >> 4;
    const float qscale = 0.17677669529663687f * 1.4426950408889634f;

    const u16* qp = qkv + ((long)b * 512 + (long)h * 128) * N;
    const u16* kp = qp + 32L * N;
    const u16* vp = qp + 64L * N;

    const int i = i0 + w * 16 + li;

    s8v qf;
    #pragma unroll
    for (int r = 0; r < 8; ++r)
        qf[r] = f2bf(bf2f(qp[(long)(8 * g + r) * N + i]) * qscale);

    f32x4 oacc[4];
    #pragma unroll
    for (int dt = 0; dt < 4; ++dt) oacc[dt] = f32x4{0.f, 0.f, 0.f, 0.f};
    float m_run = -1e30f, l_run = 0.f;

    const int kj  = lane;              // j within tile
    const int kd0 = w * 8;             // 8 d's per thread
    const int vd  = t >> 2;            // 0..63
    const int vjb = (t & 3) * 16;      // 0..48

    const int jbase = z * 576;
    u16x8 kr, vr0, vr1;
    {
        const u16* kpp = kp + jbase + kj;
        #pragma unroll
        for (int u = 0; u < 8; ++u) kr[u] = kpp[(long)(kd0 + u) * N];
        vr0 = *(const u16x8*)(vp + (long)vd * N + jbase + vjb);
        vr1 = *(const u16x8*)(vp + (long)vd * N + jbase + vjb + 8);
    }

    for (int j0 = jbase; j0 < jbase + 576; j0 += 64) {
        __syncthreads();
        *(u16x8*)&Klds[kj][kd0]     = kr;
        *(u16x8*)&Vlds[vd][vjb]     = vr0;
        *(u16x8*)&Vlds[vd][vjb + 8] = vr1;
        if (j0 + 64 < jbase + 576) {
            const u16* kpp = kp + (j0 + 64) + kj;
            #pragma unroll
            for (int u = 0; u < 8; ++u) kr[u] = kpp[(long)(kd0 + u) * N];
            vr0 = *(const u16x8*)(vp + (long)vd * N + (j0 + 64) + vjb);
            vr1 = *(const u16x8*)(vp + (long)vd * N + (j0 + 64) + vjb + 8);
        }
        __syncthreads();

        // QK^T swapped: lane holds S[j = js*16 + 4g + r][i], log2-domain
        f32x4 sacc[4];
        #pragma unroll
        for (int js = 0; js < 4; ++js) {
            s8v kf = *(const s8v*)&Klds[js * 16 + li][8 * g];
            f32x4 zz = f32x4{0.f, 0.f, 0.f, 0.f};
            sacc[js] = __builtin_amdgcn_mfma_f32_16x16x32_bf16(kf, qf, zz, 0, 0, 0);
        }

        float tm = -1e30f;
        #pragma unroll
        for (int js = 0; js < 4; ++js)
            #pragma unroll
            for (int r = 0; r < 4; ++r) tm = fmaxf(tm, sacc[js][r]);
        tm = fmaxf(tm, __shfl_xor(tm, 16, 64));
        tm = fmaxf(tm, __shfl_xor(tm, 32, 64));
        // defer-max (T13): rescale only when some row grew by >8 (log2)
        if (__any(tm > m_run + 8.f)) {
            float mnew = fmaxf(m_run, tm);
            float scl  = fexp2(m_run - mnew);
            l_run *= scl;
            #pragma unroll
            for (int dt = 0; dt < 4; ++dt) oacc[dt] *= scl;
            m_run = mnew;
        }
        float pl[4][4];
        float ts = 0.f;
        #pragma unroll
        for (int js = 0; js < 4; ++js)
            #pragma unroll
            for (int r = 0; r < 4; ++r) {
                float p = fexp2(sacc[js][r] - m_run);
                pl[js][r] = p;
                ts += p;
            }
        ts += __shfl_xor(ts, 16, 64);
        ts += __shfl_xor(ts, 32, 64);
        l_run += ts;

        // PV with k-permutation matching P's register layout
        #pragma unroll
        for (int ks = 0; ks < 2; ++ks) {
            u32x4 pw;
            pw[0] = cvtpk(pl[2 * ks][0],     pl[2 * ks][1]);
            pw[1] = cvtpk(pl[2 * ks][2],     pl[2 * ks][3]);
            pw[2] = cvtpk(pl[2 * ks + 1][0], pl[2 * ks + 1][1]);
            pw[3] = cvtpk(pl[2 * ks + 1][2], pl[2 * ks + 1][3]);
            s8v pf = __builtin_bit_cast(s8v, pw);
            #pragma unroll
            for (int dt = 0; dt < 4; ++dt) {
                int d = dt * 16 + li;
                s4v lo = *(const s4v*)&Vlds[d][32 * ks + 4 * g];
                s4v hi = *(const s4v*)&Vlds[d][32 * ks + 16 + 4 * g];
                s8v vf = __builtin_shufflevector(lo, hi, 0, 1, 2, 3, 4, 5, 6, 7);
                oacc[dt] = __builtin_amdgcn_mfma_f32_16x16x32_bf16(vf, pf, oacc[dt], 0, 0, 0);
            }
        }
    }

    // epilogue: unnormalized partial O (bf16) + m,l per (i, chunk)
    const long cb = (long)(z * 16 + bh);
    #pragma unroll
    for (int dt = 0; dt < 4; ++dt)
        #pragma unroll
        for (int r = 0; r < 4; ++r)
            Opart[(cb * 64 + dt * 16 + 4 * g + r) * N + i] = (u16)f2bf(oacc[dt][r]);
    if (g == 0) {
        mpart[cb * N + i] = m_run;
        lpart[cb * N + i] = l_run;
    }
}

// ---------------------------------------------------------------------------
// Combine split-j partials + fused depthwise-3x3 PE on v; writes transposed
// attnT [b][n][256] (bf16) so proj's GEMM gets a k-contiguous A operand.
// ---------------------------------------------------------------------------
__global__ __launch_bounds__(256) void attn_combine(
    const u16* __restrict__ Opart, const float* __restrict__ mpart,
    const float* __restrict__ lpart, const u16* __restrict__ qkv,
    const float* __restrict__ pw, const float* __restrict__ ps,
    const float* __restrict__ pb, u16* __restrict__ attnT)
{
    const int N = N_SP;
    const int i0 = blockIdx.x * 64;
    const int bh = blockIdx.y;
    const int b = bh >> 2, h = bh & 3;
    const int t = threadIdx.x;
    const int il = t & 63, dq = t >> 6;
    const int d0 = dq * 16;
    const int i = i0 + il;

    // combine weights
    float mm[4], ll[4];
    #pragma unroll
    for (int c = 0; c < 4; ++c) {
        mm[c] = mpart[((long)(c * 16 + bh)) * N + i];
        ll[c] = lpart[((long)(c * 16 + bh)) * N + i];
    }
    float ms = fmaxf(fmaxf(mm[0], mm[1]), fmaxf(mm[2], mm[3]));
    float wc[4], lsum = 0.f;
    #pragma unroll
    for (int c = 0; c < 4; ++c) {
        wc[c] = fexp2(mm[c] - ms);
        lsum += wc[c] * ll[c];
    }
    float inv = frcp(lsum);

    // PE geometry
    const int y = i / HW, x = i - (i / HW) * HW;
    const int y0ok = (y > 0), y1ok = (y < HW - 1);
    const int x0ok = (x > 0), x1ok = (x < HW - 1);
    const u16* vbase = qkv + ((long)b * 512 + (long)h * 128 + 64) * N;

    u16 ob[16];
    #pragma unroll
    for (int dd = 0; dd < 16; ++dd) {
        const int d = d0 + dd;
        const int cg = h * 64 + d;
        float o = 0.f;
        #pragma unroll
        for (int c = 0; c < 4; ++c)
            o += wc[c] * bf2f(Opart[((long)(c * 16 + bh) * 64 + d) * N + i]);
        o *= inv;
        const u16* src = vbase + (long)d * N;
        const float* w9 = pw + cg * 9;
        float s = 0.f;
        #pragma unroll
        for (int dy = -1; dy <= 1; ++dy) {
            if ((dy < 0 && !y0ok) || (dy > 0 && !y1ok)) continue;
            const u16* row = src + (y + dy) * HW;
            if (x0ok) s += w9[(dy + 1) * 3 + 0] * bf2f(row[x - 1]);
            s += w9[(dy + 1) * 3 + 1] * bf2f(row[x]);
            if (x1ok) s += w9[(dy + 1) * 3 + 2] * bf2f(row[x + 1]);
        }
        o += s * ps[cg] + pb[cg];
        ob[dd] = (u16)f2bf(o);
    }
    u16* dst = attnT + ((long)b * N + i) * 256 + h * 64 + d0;
    *(u16x8*)dst       = *(u16x8*)&ob[0];
    *(u16x8*)(dst + 8) = *(u16x8*)&ob[8];
}

// ---------------------------------------------------------------------------
extern "C" void kernel_launch(void* const* d_in, const int* in_sizes, int n_in,
                              void* d_out, int out_size, void* d_ws, size_t ws_size,
                              hipStream_t stream)
{
    const long N = N_SP;
    const float* x      = (const float*)d_in[0];
    const float* cv1_w  = (const float*)d_in[1];
    const float* cv1_s  = (const float*)d_in[2];
    const float* cv1_b  = (const float*)d_in[3];
    const float* qkv_w  = (const float*)d_in[4];
    const float* qkv_s  = (const float*)d_in[5];
    const float* qkv_b  = (const float*)d_in[6];
    const float* pe_w   = (const float*)d_in[7];
    const float* pe_s   = (const float*)d_in[8];
    const float* pe_b   = (const float*)d_in[9];
    const float* proj_w = (const float*)d_in[10];
    const float* proj_s = (const float*)d_in[11];
    const float* proj_b = (const float*)d_in[12];
    const float* ffn1_w = (const float*)d_in[13];
    const float* ffn1_s = (const float*)d_in[14];
    const float* ffn1_b = (const float*)d_in[15];
    const float* ffn2_w = (const float*)d_in[16];
    const float* ffn2_s = (const float*)d_in[17];
    const float* ffn2_b = (const float*)d_in[18];
    const float* cv2_w  = (const float*)d_in[19];
    const float* cv2_s  = (const float*)d_in[20];
    const float* cv2_b  = (const float*)d_in[21];
    float* out = (float*)d_out;

    u16* ws = (u16*)d_ws;
    u16* xT      = ws;                       // [4][2304][512]
    u16* abT     = xT      + 4L * N * 512;   // [4][2304][512]
    u16* qkvb    = abT     + 4L * N * 512;   // [4][512][2304]
    u16* attnT   = qkvb    + 4L * N * 512;   // [4][2304][256]
    u16* bb2T    = attnT   + 4L * N * 256;   // [4][2304][256]
    u16* fT      = bb2T    + 4L * N * 256;   // [4][2304][512]
    u16* bb3T    = fT      + 4L * N * 512;   // [4][2304][256]
    u16* w_cv1   = bb3T    + 4L * N * 256;   // 512*512
    u16* w_qkv   = w_cv1   + 512L * 512;
    u16* w_proj  = w_qkv   + 512L * 256;
    u16* w_ffn1  = w_proj  + 256L * 256;
    u16* w_ffn2  = w_ffn1  + 512L * 256;
    u16* w_cv2   = w_ffn2  + 256L * 512;
    u16* Opart   = w_cv2   + 512L * 512;     // [4][16][64][2304] bf16
    float* mpart = (float*)(Opart + 4L * 16 * 64 * N);   // [4][16][2304]
    float* lpart = mpart + 4L * 16 * N;

    dim3 blk(256);
    const int BIGK = 1 << 28;

    cvt_w<<<960, blk, 0, stream>>>(cv1_w, qkv_w, proj_w, ffn1_w, ffn2_w, cv2_w,
                                   w_cv1, w_qkv, w_proj, w_ffn1, w_ffn2, w_cv2);
    transpose_x<<<dim3(36, 8, 4), blk, 0, stream>>>(x, xT);

    // 1. abT = silu(cv1(x))^T
    mfma_gemm<0><<<dim3(144, 8), blk, 0, stream>>>(
        xT, nullptr, BIGK, 512, 0, 512, w_cv1, cv1_s, cv1_b,
        nullptr, 0, abT, 512, 512, 1);

    // 2. qkvb = conv(bb) normal orientation [b][512][N]
    mfma_gemm<1><<<dim3(144, 8), blk, 0, stream>>>(
        abT + 256, nullptr, BIGK, 512, 0, 256, w_qkv, qkv_s, qkv_b,
        nullptr, 0, qkvb, 0, 512, 0);

    // 3. attention partials (split-j x4)
    attn_mfma<<<dim3(36, 16, 4), blk, 0, stream>>>(qkvb, Opart, mpart, lpart);

    // 4. combine + fused PE -> attnT [b][n][256]
    attn_combine<<<dim3(36, 16), blk, 0, stream>>>(
        Opart, mpart, lpart, qkvb, pe_w, pe_s, pe_b, attnT);

    // 5. bb2T = bb^T + proj(attn)^T
    mfma_gemm<0><<<dim3(144, 4), blk, 0, stream>>>(
        attnT, nullptr, BIGK, 256, 0, 256, w_proj, proj_s, proj_b,
        abT + 256, 512, bb2T, 256, 256, 0);

    // 6. fT = silu(ffn1(bb2))^T
    mfma_gemm<0><<<dim3(144, 8), blk, 0, stream>>>(
        bb2T, nullptr, BIGK, 256, 0, 256, w_ffn1, ffn1_s, ffn1_b,
        nullptr, 0, fT, 512, 512, 1);

    // 7. bb3T = bb2T + ffn2(f)^T
    mfma_gemm<0><<<dim3(144, 4), blk, 0, stream>>>(
        fT, nullptr, BIGK, 512, 0, 512, w_ffn2, ffn2_s, ffn2_b,
        bb2T, 256, bb3T, 256, 256, 0);

    // 8. out = silu(cv2(concat(a, bb3)))  fp32 normal [b][512][N]
    mfma_gemm<2><<<dim3(144, 8), blk, 0, stream>>>(
        abT, bb3T, 256, 512, 256, 512, w_cv2, cv2_s, cv2_b,
        nullptr, 0, out, 0, 512, 1);
}

// Round 7
// 147.627 us; speedup vs baseline: 48.2305x; 1.0539x over previous
//
#include <hip/hip_runtime.h>
#include <math.h>

#define N_SP 2304   // 48*48 spatial
#define HW 48

typedef unsigned short u16;
typedef short s8v  __attribute__((ext_vector_type(8)));   // bf16x8 (MFMA operand)
typedef short s4v  __attribute__((ext_vector_type(4)));   // bf16x4
typedef u16   u16x8 __attribute__((ext_vector_type(8)));
typedef float f32x4 __attribute__((ext_vector_type(4)));
typedef unsigned u32x4 __attribute__((ext_vector_type(4)));

__device__ __forceinline__ short f2bf(float x) {
    unsigned u = __float_as_uint(x);
    u += 0x7FFFu + ((u >> 16) & 1u);
    return (short)(u >> 16);
}
__device__ __forceinline__ float bf2f(u16 u) {
    return __uint_as_float((unsigned)u << 16);
}
__device__ __forceinline__ float fexp2(float x) { return __builtin_amdgcn_exp2f(x); }
__device__ __forceinline__ float frcp(float x)  { return __builtin_amdgcn_rcpf(x); }
__device__ __forceinline__ float fsilu(float v) {
    return v * frcp(1.f + fexp2(-1.4426950408889634f * v));
}
__device__ __forceinline__ unsigned cvtpk(float lo, float hi) {  // 2xf32 -> packed bf16
    unsigned r;
    asm("v_cvt_pk_bf16_f32 %0, %1, %2" : "=v"(r) : "v"(lo), "v"(hi));
    return r;
}
__device__ __forceinline__ void gload16(const void* g, void* l) {
    __builtin_amdgcn_global_load_lds(
        (const __attribute__((address_space(1))) void*)g,
        (__attribute__((address_space(3))) void*)l, 16, 0, 0);
}

// ---------------------------------------------------------------------------
// Weight fp32 -> bf16 (all six weight matrices in one launch, float4 chunks)
// ---------------------------------------------------------------------------
__global__ __launch_bounds__(256) void cvt_w(
    const float* __restrict__ s0, const float* __restrict__ s1,
    const float* __restrict__ s2, const float* __restrict__ s3,
    const float* __restrict__ s4, const float* __restrict__ s5,
    u16* __restrict__ d0, u16* __restrict__ d1, u16* __restrict__ d2,
    u16* __restrict__ d3, u16* __restrict__ d4, u16* __restrict__ d5)
{
    int id = blockIdx.x * 256 + threadIdx.x;   // float4 index
    const int c0 = 65536, c1 = c0 + 32768, c2 = c1 + 16384,
              c3 = c2 + 32768, c4 = c3 + 32768, c5 = c4 + 65536;
    if (id >= c5) return;
    const float* s; u16* d; int off;
    if      (id < c0) { s = s0; d = d0; off = id; }
    else if (id < c1) { s = s1; d = d1; off = id - c0; }
    else if (id < c2) { s = s2; d = d2; off = id - c1; }
    else if (id < c3) { s = s3; d = d3; off = id - c2; }
    else if (id < c4) { s = s4; d = d4; off = id - c3; }
    else              { s = s5; d = d5; off = id - c4; }
    float4 v = ((const float4*)s)[off];
    s4v p; p[0] = f2bf(v.x); p[1] = f2bf(v.y); p[2] = f2bf(v.z); p[3] = f2bf(v.w);
    ((s4v*)d)[off] = p;
}

// ---------------------------------------------------------------------------
// x [b][512][2304] fp32  ->  xT [b][2304][512] bf16  (LDS-tiled transpose)
// ---------------------------------------------------------------------------
__global__ __launch_bounds__(256) void transpose_x(const float* __restrict__ X,
                                                   u16* __restrict__ XT)
{
    __shared__ float tile[64][65];
    const int n0 = blockIdx.x * 64, c0 = blockIdx.y * 64, b = blockIdx.z;
    const float* src = X + (long)b * 512 * N_SP;
    u16* dst = XT + (long)b * N_SP * 512;
    const int t = threadIdx.x;
    #pragma unroll
    for (int it = 0; it < 16; ++it) {
        int id = t + 256 * it;
        int cl = id >> 6, nl = id & 63;
        tile[cl][nl] = src[(long)(c0 + cl) * N_SP + n0 + nl];
    }
    __syncthreads();
    #pragma unroll
    for (int it = 0; it < 16; ++it) {
        int id = t + 256 * it;
        int nl = id >> 6, cl = id & 63;
        dst[(long)(n0 + nl) * 512 + c0 + cl] = f2bf(tile[cl][nl]);
    }
}

// ---------------------------------------------------------------------------
// MFMA GEMM: Y^T[n][o] = act((X^T W^T)*S + B) (+Res), bf16.
// Tile 128(n) x BN_(o), BK=64. T2 XOR-swizzle (chunk ^= row&7) applied via
// pre-swizzled GLOBAL source for global_load_lds (rule #21) + swizzled
// ds_read -> conflict-floor b128 reads. T3-minimum 2-phase: raw s_barrier,
// vmcnt(0) only AFTER the MFMA cluster, so next-tile loads hide under compute.
// OMODE: 0 = Y^T bf16 [n][sO]; 1 = normal bf16 [b][Mtot][2304]; 2 = f32.
// ---------------------------------------------------------------------------
template <int BN_, int OMODE>
__global__ __launch_bounds__(256) void mfma_gemm(
    const u16* __restrict__ A1, const u16* __restrict__ A2, int K1,
    int sA1, int sA2, int K,
    const u16* __restrict__ W,
    const float* __restrict__ S, const float* __restrict__ Bi,
    const u16* __restrict__ Res, int sR,
    void* __restrict__ OutP, int sO, int Mtot,
    int act)
{
    constexpr int NFN = BN_ / 32;            // B fragments per wave (o dir)
    __shared__ u16 Al[2][128][64];
    __shared__ u16 Bl[2][BN_][64];
    const int t  = threadIdx.x;
    const int n0 = blockIdx.x * 128;
    const int o0 = blockIdx.y * BN_;
    const int lane = t & 63, w = t >> 6;
    const int wn = (w & 1) * 64, wo = (w >> 1) * (BN_ / 2);
    const int li = lane & 15, g = lane >> 4;

    const int b_blk = n0 / N_SP;             // 2304 % 128 == 0
    const int n_in0 = n0 - b_blk * N_SP;

    f32x4 acc[4][NFN];
    #pragma unroll
    for (int fm = 0; fm < 4; ++fm)
        #pragma unroll
        for (int fn = 0; fn < NFN; ++fn) acc[fm][fn] = f32x4{0.f, 0.f, 0.f, 0.f};

    // stage one K-step (BK=64) into buf: A 1024 chunks (4/thr), B BN_*8 (NFN*... )
    auto issue = [&](int buf, int k0) {
        #pragma unroll
        for (int q = 0; q < 4; ++q) {
            int c = t + q * 256;
            int row = c >> 3;
            int col = ((c & 7) ^ (row & 7)) * 8;   // inverse-swizzled source
            int kk = k0 + col;
            const u16* ga = (kk < K1) ? (A1 + (long)(n0 + row) * sA1 + kk)
                                      : (A2 + (long)(n0 + row) * sA2 + (kk - K1));
            gload16(ga, (u16*)Al[buf] + (q * 256 + w * 64) * 8);
        }
        #pragma unroll
        for (int q = 0; q < NFN; ++q) {
            int c = t + q * 256;
            int row = c >> 3;
            int col = ((c & 7) ^ (row & 7)) * 8;
            gload16(W + (long)(o0 + row) * K + k0 + col,
                    (u16*)Bl[buf] + (q * 256 + w * 64) * 8);
        }
    };

    issue(0, 0);
    asm volatile("s_waitcnt vmcnt(0)" ::: "memory");
    __builtin_amdgcn_s_barrier();

    int cur = 0;
    const int NK = K >> 6;
    for (int ks = 0; ks < NK; ++ks) {
        if (ks + 1 < NK) issue(cur ^ 1, (ks + 1) << 6);   // in flight over compute
        #pragma unroll
        for (int k2 = 0; k2 < 2; ++k2) {
            s8v af[4], bfv[NFN];
            #pragma unroll
            for (int fm = 0; fm < 4; ++fm) {
                int row = wn + fm * 16 + li;
                af[fm] = *(const s8v*)&Al[cur][row][((g + 4 * k2) ^ (li & 7)) * 8];
            }
            #pragma unroll
            for (int fn = 0; fn < NFN; ++fn) {
                int row = wo + fn * 16 + li;
                bfv[fn] = *(const s8v*)&Bl[cur][row][((g + 4 * k2) ^ (li & 7)) * 8];
            }
            #pragma unroll
            for (int fm = 0; fm < 4; ++fm)
                #pragma unroll
                for (int fn = 0; fn < NFN; ++fn)
                    acc[fm][fn] = __builtin_amdgcn_mfma_f32_16x16x32_bf16(
                        af[fm], bfv[fn], acc[fm][fn], 0, 0, 0);
        }
        asm volatile("s_waitcnt vmcnt(0)" ::: "memory");
        __builtin_amdgcn_s_barrier();
        cur ^= 1;
    }

    #pragma unroll
    for (int fn = 0; fn < NFN; ++fn) {
        const int o = o0 + wo + fn * 16 + li;
        const float sc2 = S[o], bi = Bi[o];
        #pragma unroll
        for (int fm = 0; fm < 4; ++fm) {
            const int nb  = n0 + wn + fm * 16 + 4 * g;
            const int nib = n_in0 + wn + fm * 16 + 4 * g;
            float y[4];
            #pragma unroll
            for (int r = 0; r < 4; ++r) {
                float v = acc[fm][fn][r] * sc2 + bi;
                if (act) v = fsilu(v);
                y[r] = v;
            }
            if (Res) {
                #pragma unroll
                for (int r = 0; r < 4; ++r)
                    y[r] += bf2f(Res[(long)(nb + r) * sR + o]);
            }
            if (OMODE == 0) {
                u16* O = (u16*)OutP;
                #pragma unroll
                for (int r = 0; r < 4; ++r)
                    O[(long)(nb + r) * sO + o] = (u16)f2bf(y[r]);
            } else if (OMODE == 1) {
                u16* O = (u16*)OutP + (long)b_blk * Mtot * N_SP + (long)o * N_SP + nib;
                s4v pk;
                #pragma unroll
                for (int r = 0; r < 4; ++r) pk[r] = f2bf(y[r]);
                *(s4v*)O = pk;
            } else {
                float* O = (float*)OutP + (long)b_blk * Mtot * N_SP + (long)o * N_SP + nib;
                *(float4*)O = make_float4(y[0], y[1], y[2], y[3]);
            }
        }
    }
}

// ---------------------------------------------------------------------------
// MFMA flash attention, split-j x4, TWO query-fragments per wave (block =
// 128 queries): K/V LDS reads are shared across both q-frags -> LDS
// bytes/query halved (R5 showed the kernel LDS-throughput-bound).
// P written back into sacc (no extra register array).
// ---------------------------------------------------------------------------
__global__ __launch_bounds__(256) void attn_mfma(const u16* __restrict__ qkv,
    u16* __restrict__ Opart, float* __restrict__ mpart, float* __restrict__ lpart)
{
    const int N = N_SP;
    __shared__ u16 Klds[64][40];   // [j][d]
    __shared__ u16 Vlds[64][72];   // [d][j]

    const int i0 = blockIdx.x * 128;
    const int bh = blockIdx.y;
    const int z  = blockIdx.z;      // j-chunk
    const int b = bh >> 2, h = bh & 3;
    const int t = threadIdx.x;
    const int w = t >> 6;
    const int lane = t & 63;
    const int li = lane & 15;
    const int g  = lane >> 4;
    const float qscale = 0.17677669529663687f * 1.4426950408889634f;

    const u16* qp = qkv + ((long)b * 512 + (long)h * 128) * N;
    const u16* kp = qp + 32L * N;
    const u16* vp = qp + 64L * N;

    const int ia = i0 + w * 16 + li;     // q-frag 0
    const int ib = ia + 64;              // q-frag 1

    s8v qf[2];
    #pragma unroll
    for (int r = 0; r < 8; ++r) {
        qf[0][r] = f2bf(bf2f(qp[(long)(8 * g + r) * N + ia]) * qscale);
        qf[1][r] = f2bf(bf2f(qp[(long)(8 * g + r) * N + ib]) * qscale);
    }

    f32x4 oacc[2][4];
    #pragma unroll
    for (int q = 0; q < 2; ++q)
        #pragma unroll
        for (int dt = 0; dt < 4; ++dt) oacc[q][dt] = f32x4{0.f, 0.f, 0.f, 0.f};
    float m_run[2] = {-1e30f, -1e30f}, l_run[2] = {0.f, 0.f};

    const int kj  = lane;              // j within tile
    const int kd0 = w * 8;             // 8 d's per thread
    const int vd  = t >> 2;            // 0..63
    const int vjb = (t & 3) * 16;      // 0..48

    const int jbase = z * 576;
    u16x8 kr, vr0, vr1;
    {
        const u16* kpp = kp + jbase + kj;
        #pragma unroll
        for (int u = 0; u < 8; ++u) kr[u] = kpp[(long)(kd0 + u) * N];
        vr0 = *(const u16x8*)(vp + (long)vd * N + jbase + vjb);
        vr1 = *(const u16x8*)(vp + (long)vd * N + jbase + vjb + 8);
    }

    for (int j0 = jbase; j0 < jbase + 576; j0 += 64) {
        __syncthreads();
        *(u16x8*)&Klds[kj][kd0]     = kr;
        *(u16x8*)&Vlds[vd][vjb]     = vr0;
        *(u16x8*)&Vlds[vd][vjb + 8] = vr1;
        if (j0 + 64 < jbase + 576) {
            const u16* kpp = kp + (j0 + 64) + kj;
            #pragma unroll
            for (int u = 0; u < 8; ++u) kr[u] = kpp[(long)(kd0 + u) * N];
            vr0 = *(const u16x8*)(vp + (long)vd * N + (j0 + 64) + vjb);
            vr1 = *(const u16x8*)(vp + (long)vd * N + (j0 + 64) + vjb + 8);
        }
        __syncthreads();

        // QK^T swapped, both q-frags share each K fragment read
        f32x4 sacc[2][4];
        #pragma unroll
        for (int js = 0; js < 4; ++js) {
            s8v kf = *(const s8v*)&Klds[js * 16 + li][8 * g];
            f32x4 zz = f32x4{0.f, 0.f, 0.f, 0.f};
            sacc[0][js] = __builtin_amdgcn_mfma_f32_16x16x32_bf16(kf, qf[0], zz, 0, 0, 0);
            sacc[1][js] = __builtin_amdgcn_mfma_f32_16x16x32_bf16(kf, qf[1], zz, 0, 0, 0);
        }

        // online softmax per q-frag; P overwrites sacc
        #pragma unroll
        for (int q = 0; q < 2; ++q) {
            float tm = -1e30f;
            #pragma unroll
            for (int js = 0; js < 4; ++js)
                #pragma unroll
                for (int r = 0; r < 4; ++r) tm = fmaxf(tm, sacc[q][js][r]);
            tm = fmaxf(tm, __shfl_xor(tm, 16, 64));
            tm = fmaxf(tm, __shfl_xor(tm, 32, 64));
            if (__any(tm > m_run[q] + 8.f)) {     // defer-max (T13)
                float mnew = fmaxf(m_run[q], tm);
                float scl  = fexp2(m_run[q] - mnew);
                l_run[q] *= scl;
                #pragma unroll
                for (int dt = 0; dt < 4; ++dt) oacc[q][dt] *= scl;
                m_run[q] = mnew;
            }
            float ts = 0.f;
            #pragma unroll
            for (int js = 0; js < 4; ++js)
                #pragma unroll
                for (int r = 0; r < 4; ++r) {
                    float p = fexp2(sacc[q][js][r] - m_run[q]);
                    sacc[q][js][r] = p;
                    ts += p;
                }
            ts += __shfl_xor(ts, 16, 64);
            ts += __shfl_xor(ts, 32, 64);
            l_run[q] += ts;
        }

        // PV: V fragments shared across q-frags; k-permutation matches P layout
        #pragma unroll
        for (int ks = 0; ks < 2; ++ks) {
            s8v pf[2];
            #pragma unroll
            for (int q = 0; q < 2; ++q) {
                u32x4 pw;
                pw[0] = cvtpk(sacc[q][2 * ks][0],     sacc[q][2 * ks][1]);
                pw[1] = cvtpk(sacc[q][2 * ks][2],     sacc[q][2 * ks][3]);
                pw[2] = cvtpk(sacc[q][2 * ks + 1][0], sacc[q][2 * ks + 1][1]);
                pw[3] = cvtpk(sacc[q][2 * ks + 1][2], sacc[q][2 * ks + 1][3]);
                pf[q] = __builtin_bit_cast(s8v, pw);
            }
            #pragma unroll
            for (int dt = 0; dt < 4; ++dt) {
                int d = dt * 16 + li;
                s4v lo = *(const s4v*)&Vlds[d][32 * ks + 4 * g];
                s4v hi = *(const s4v*)&Vlds[d][32 * ks + 16 + 4 * g];
                s8v vf = __builtin_shufflevector(lo, hi, 0, 1, 2, 3, 4, 5, 6, 7);
                oacc[0][dt] = __builtin_amdgcn_mfma_f32_16x16x32_bf16(vf, pf[0], oacc[0][dt], 0, 0, 0);
                oacc[1][dt] = __builtin_amdgcn_mfma_f32_16x16x32_bf16(vf, pf[1], oacc[1][dt], 0, 0, 0);
            }
        }
    }

    // epilogue: unnormalized partial O (bf16) + m,l per (i, chunk)
    const long cb = (long)(z * 16 + bh);
    #pragma unroll
    for (int q = 0; q < 2; ++q) {
        const int i = q ? ib : ia;
        #pragma unroll
        for (int dt = 0; dt < 4; ++dt)
            #pragma unroll
            for (int r = 0; r < 4; ++r)
                Opart[(cb * 64 + dt * 16 + 4 * g + r) * N + i] = (u16)f2bf(oacc[q][dt][r]);
        if (g == 0) {
            mpart[cb * N + i] = m_run[q];
            lpart[cb * N + i] = l_run[q];
        }
    }
}

// ---------------------------------------------------------------------------
// Combine split-j partials + fused depthwise-3x3 PE on v; writes transposed
// attnT [b][n][256] (bf16) so proj's GEMM gets a k-contiguous A operand.
// ---------------------------------------------------------------------------
__global__ __launch_bounds__(256) void attn_combine(
    const u16* __restrict__ Opart, const float* __restrict__ mpart,
    const float* __restrict__ lpart, const u16* __restrict__ qkv,
    const float* __restrict__ pw, const float* __restrict__ ps,
    const float* __restrict__ pb, u16* __restrict__ attnT)
{
    const int N = N_SP;
    const int i0 = blockIdx.x * 64;
    const int bh = blockIdx.y;
    const int b = bh >> 2, h = bh & 3;
    const int t = threadIdx.x;
    const int il = t & 63, dq = t >> 6;
    const int d0 = dq * 16;
    const int i = i0 + il;

    float mm[4], ll[4];
    #pragma unroll
    for (int c = 0; c < 4; ++c) {
        mm[c] = mpart[((long)(c * 16 + bh)) * N + i];
        ll[c] = lpart[((long)(c * 16 + bh)) * N + i];
    }
    float ms = fmaxf(fmaxf(mm[0], mm[1]), fmaxf(mm[2], mm[3]));
    float wc[4], lsum = 0.f;
    #pragma unroll
    for (int c = 0; c < 4; ++c) {
        wc[c] = fexp2(mm[c] - ms);
        lsum += wc[c] * ll[c];
    }
    float inv = frcp(lsum);

    const int y = i / HW, x = i - (i / HW) * HW;
    const int y0ok = (y > 0), y1ok = (y < HW - 1);
    const int x0ok = (x > 0), x1ok = (x < HW - 1);
    const u16* vbase = qkv + ((long)b * 512 + (long)h * 128 + 64) * N;

    u16 ob[16];
    #pragma unroll
    for (int dd = 0; dd < 16; ++dd) {
        const int d = d0 + dd;
        const int cg = h * 64 + d;
        float o = 0.f;
        #pragma unroll
        for (int c = 0; c < 4; ++c)
            o += wc[c] * bf2f(Opart[((long)(c * 16 + bh) * 64 + d) * N + i]);
        o *= inv;
        const u16* src = vbase + (long)d * N;
        const float* w9 = pw + cg * 9;
        float s = 0.f;
        #pragma unroll
        for (int dy = -1; dy <= 1; ++dy) {
            if ((dy < 0 && !y0ok) || (dy > 0 && !y1ok)) continue;
            const u16* row = src + (y + dy) * HW;
            if (x0ok) s += w9[(dy + 1) * 3 + 0] * bf2f(row[x - 1]);
            s += w9[(dy + 1) * 3 + 1] * bf2f(row[x]);
            if (x1ok) s += w9[(dy + 1) * 3 + 2] * bf2f(row[x + 1]);
        }
        o += s * ps[cg] + pb[cg];
        ob[dd] = (u16)f2bf(o);
    }
    u16* dst = attnT + ((long)b * N + i) * 256 + h * 64 + d0;
    *(u16x8*)dst       = *(u16x8*)&ob[0];
    *(u16x8*)(dst + 8) = *(u16x8*)&ob[8];
}

// ---------------------------------------------------------------------------
extern "C" void kernel_launch(void* const* d_in, const int* in_sizes, int n_in,
                              void* d_out, int out_size, void* d_ws, size_t ws_size,
                              hipStream_t stream)
{
    const long N = N_SP;
    const float* x      = (const float*)d_in[0];
    const float* cv1_w  = (const float*)d_in[1];
    const float* cv1_s  = (const float*)d_in[2];
    const float* cv1_b  = (const float*)d_in[3];
    const float* qkv_w  = (const float*)d_in[4];
    const float* qkv_s  = (const float*)d_in[5];
    const float* qkv_b  = (const float*)d_in[6];
    const float* pe_w   = (const float*)d_in[7];
    const float* pe_s   = (const float*)d_in[8];
    const float* pe_b   = (const float*)d_in[9];
    const float* proj_w = (const float*)d_in[10];
    const float* proj_s = (const float*)d_in[11];
    const float* proj_b = (const float*)d_in[12];
    const float* ffn1_w = (const float*)d_in[13];
    const float* ffn1_s = (const float*)d_in[14];
    const float* ffn1_b = (const float*)d_in[15];
    const float* ffn2_w = (const float*)d_in[16];
    const float* ffn2_s = (const float*)d_in[17];
    const float* ffn2_b = (const float*)d_in[18];
    const float* cv2_w  = (const float*)d_in[19];
    const float* cv2_s  = (const float*)d_in[20];
    const float* cv2_b  = (const float*)d_in[21];
    float* out = (float*)d_out;

    u16* ws = (u16*)d_ws;
    u16* xT      = ws;                       // [4][2304][512]
    u16* abT     = xT      + 4L * N * 512;   // [4][2304][512]
    u16* qkvb    = abT     + 4L * N * 512;   // [4][512][2304]
    u16* attnT   = qkvb    + 4L * N * 512;   // [4][2304][256]
    u16* bb2T    = attnT   + 4L * N * 256;   // [4][2304][256]
    u16* fT      = bb2T    + 4L * N * 256;   // [4][2304][512]
    u16* bb3T    = fT      + 4L * N * 512;   // [4][2304][256]
    u16* w_cv1   = bb3T    + 4L * N * 256;   // 512*512
    u16* w_qkv   = w_cv1   + 512L * 512;
    u16* w_proj  = w_qkv   + 512L * 256;
    u16* w_ffn1  = w_proj  + 256L * 256;
    u16* w_ffn2  = w_ffn1  + 512L * 256;
    u16* w_cv2   = w_ffn2  + 256L * 512;
    u16* Opart   = w_cv2   + 512L * 512;     // [4][16][64][2304] bf16
    float* mpart = (float*)(Opart + 4L * 16 * 64 * N);   // [4][16][2304]
    float* lpart = mpart + 4L * 16 * N;

    dim3 blk(256);
    const int BIGK = 1 << 28;

    cvt_w<<<960, blk, 0, stream>>>(cv1_w, qkv_w, proj_w, ffn1_w, ffn2_w, cv2_w,
                                   w_cv1, w_qkv, w_proj, w_ffn1, w_ffn2, w_cv2);
    transpose_x<<<dim3(36, 8, 4), blk, 0, stream>>>(x, xT);

    // 1. abT = silu(cv1(x))^T
    mfma_gemm<64, 0><<<dim3(72, 8), blk, 0, stream>>>(
        xT, nullptr, BIGK, 512, 0, 512, w_cv1, cv1_s, cv1_b,
        nullptr, 0, abT, 512, 512, 1);

    // 2. qkvb = conv(bb) normal orientation [b][512][N]
    mfma_gemm<64, 1><<<dim3(72, 8), blk, 0, stream>>>(
        abT + 256, nullptr, BIGK, 512, 0, 256, w_qkv, qkv_s, qkv_b,
        nullptr, 0, qkvb, 0, 512, 0);

    // 3. attention partials (split-j x4, 128 queries/block)
    attn_mfma<<<dim3(18, 16, 4), blk, 0, stream>>>(qkvb, Opart, mpart, lpart);

    // 4. combine + fused PE -> attnT [b][n][256]
    attn_combine<<<dim3(36, 16), blk, 0, stream>>>(
        Opart, mpart, lpart, qkvb, pe_w, pe_s, pe_b, attnT);

    // 5. bb2T = bb^T + proj(attn)^T
    mfma_gemm<32, 0><<<dim3(72, 8), blk, 0, stream>>>(
        attnT, nullptr, BIGK, 256, 0, 256, w_proj, proj_s, proj_b,
        abT + 256, 512, bb2T, 256, 256, 0);

    // 6. fT = silu(ffn1(bb2))^T
    mfma_gemm<64, 0><<<dim3(72, 8), blk, 0, stream>>>(
        bb2T, nullptr, BIGK, 256, 0, 256, w_ffn1, ffn1_s, ffn1_b,
        nullptr, 0, fT, 512, 512, 1);

    // 7. bb3T = bb2T + ffn2(f)^T
    mfma_gemm<32, 0><<<dim3(72, 8), blk, 0, stream>>>(
        fT, nullptr, BIGK, 512, 0, 512, w_ffn2, ffn2_s, ffn2_b,
        bb2T, 256, bb3T, 256, 256, 0);

    // 8. out = silu(cv2(concat(a, bb3)))  fp32 normal [b][512][N]
    mfma_gemm<64, 2><<<dim3(72, 8), blk, 0, stream>>>(
        abT, bb3T, 256, 512, 256, 512, w_cv2, cv2_s, cv2_b,
        nullptr, 0, out, 0, 512, 1);
}